// Round 15
// baseline (296.591 us; speedup 1.0000x reference)
//
#include <hip/hip_runtime.h>
#include <math.h>

#define B_ 32
#define N_ 4096
#define D_ 64
#define T_ 12
#define EPS_ 1e-7f
#define PSTR 65
#define ESTR 72   // e-plane LDS row stride in SHORTS (144B, 16B-aligned)

typedef float4 f4;
#define LD4(p) (*(const float4*)(p))

typedef __attribute__((ext_vector_type(8))) short short8;
typedef __attribute__((ext_vector_type(4))) short s4b;
typedef __attribute__((ext_vector_type(4))) float f32x4;
#define MFMA(a, b, c)   __builtin_amdgcn_mfma_f32_16x16x32_bf16(a, b, c, 0, 0, 0)
#define MFMA16(a, b, c) __builtin_amdgcn_mfma_f32_16x16x16bf16_1k(a, b, c, 0, 0, 0)

// weight blob offsets (shorts) in global wblob
#define OFF_C1H 0
#define OFF_C1L 8192
#define OFF_B1H 16384
#define OFF_B1L 24576
#define OFF_C2TH 32768
#define OFF_C2TL 36864
#define OFF_B2TH 40960
#define OFF_B2TL 45056
#define WBLOB_SHORTS 49152

__device__ __forceinline__ float f4c(const float4 v, int q) {
    return q == 0 ? v.x : q == 1 ? v.y : q == 2 ? v.z : v.w;
}
__device__ __forceinline__ void fma8(float (&acc)[8], float a, const float4 w0, const float4 w1) {
    acc[0] = fmaf(a, w0.x, acc[0]); acc[1] = fmaf(a, w0.y, acc[1]);
    acc[2] = fmaf(a, w0.z, acc[2]); acc[3] = fmaf(a, w0.w, acc[3]);
    acc[4] = fmaf(a, w1.x, acc[4]); acc[5] = fmaf(a, w1.y, acc[5]);
    acc[6] = fmaf(a, w1.z, acc[6]); acc[7] = fmaf(a, w1.w, acc[7]);
}

__device__ __forceinline__ void splitbf(float a, short& h, short& l) {
    unsigned x = __float_as_uint(a);
    h = (short)(x >> 16);
    float r = a - __uint_as_float(x & 0xffff0000u);
    l = (short)(__float_as_uint(r) >> 16);
}

// sigma: involutive feature permutation for e-storage (swap bits[5:4]<->[3:2])
__device__ __forceinline__ int sigma_(int f) {
    return (((f >> 2) & 3) << 4) | (((f >> 4) & 3) << 2) | (f & 3);
}

// ---------------------------------------------------------------------------
// Prep (parallel): blocks 0-31 w1 packs, 32-47 w2^T packs, 48 contrib.
// ---------------------------------------------------------------------------
__global__ void prep_kernel(
    const float* __restrict__ cn_w1, const float* __restrict__ cn_w2,
    const float* __restrict__ bn_w1, const float* __restrict__ bn_w2,
    const float* __restrict__ bn_b1, const float* __restrict__ label_emb,
    short* __restrict__ wblob, float* __restrict__ contrib)
{
    const int bid = blockIdx.x, tid = threadIdx.x;
    if (bid < 32) {                                  // w1 packs (K=128)
        const int idx = bid * 256 + tid;
        const int e = idx & 7, l = (idx >> 3) & 63, fb = idx >> 9;
        const int kt = fb >> 2, mt = fb & 3;
        const int f_lin = (kt & 1) * 32 + (l >> 4) * 8 + e;
        const int k = (kt >> 1) * 64 + sigma_(f_lin);
        const int n = mt * 16 + (l & 15);
        short h, lo;
        splitbf(cn_w1[k * 64 + n], h, lo);
        wblob[OFF_C1H + idx] = h; wblob[OFF_C1L + idx] = lo;
        splitbf(bn_w1[k * 64 + n], h, lo);
        wblob[OFF_B1H + idx] = h; wblob[OFF_B1L + idx] = lo;
    } else if (bid < 48) {                           // w2^T packs (16x16x16 A)
        const int idx = (bid - 32) * 256 + tid;
        const int e = idx & 3, l = (idx >> 2) & 63, fb = idx >> 8;
        const int ks = fb >> 2, mt2 = fb & 3;
        const int k = ks * 16 + (l >> 4) * 4 + e;
        const int n = mt2 * 16 + (l & 15);
        short h, lo;
        splitbf(cn_w2[k * 64 + n], h, lo);
        wblob[OFF_C2TH + idx] = h; wblob[OFF_C2TL + idx] = lo;
        splitbf(bn_w2[k * 64 + n], h, lo);
        wblob[OFF_B2TH + idx] = h; wblob[OFF_B2TL + idx] = lo;
    } else if (tid < 128) {                          // contrib
        const int c = tid >> 6, n = tid & 63;
        float s = bn_b1[n];
#pragma unroll 8
        for (int kk = 0; kk < 64; ++kk)
            s = fmaf(label_emb[c * 64 + kk], bn_w1[(128 + kk) * 64 + n], s);
        contrib[c * 64 + n] = s;
    }
}

// ---------------------------------------------------------------------------
// Embedding (fp32 vector, w2 staged in LDS). Writes e planes in sigma order.
// ---------------------------------------------------------------------------
__global__ __launch_bounds__(256, 3) void emb_kernel(
    const int* __restrict__ x, const float* __restrict__ y,
    const float* __restrict__ w1, const float* __restrict__ b1,
    const float* __restrict__ w2, const float* __restrict__ b2,
    short* __restrict__ e_hi, short* __restrict__ e_lo, int* __restrict__ v_out)
{
    __shared__ float h_lds[128 * PSTR];
    __shared__ __align__(16) float w2s[4096];   // 16 KB
    const int tid = threadIdx.x;
    const int s   = tid & 7;
    const int g   = tid >> 3;
    const int jj0 = s * 8;
    const int i0  = (blockIdx.x * 32 + g) * 4;

    {   // stage w2 into LDS (covered by the barrier below)
        float4* d = (float4*)w2s;
        const float4* sp = (const float4*)w2;
#pragma unroll
        for (int i = 0; i < 4; ++i)
            d[tid + i * 256] = sp[tid + i * 256];
    }

    {
        f4 wa0 = LD4(w1 + jj0),      wa1 = LD4(w1 + jj0 + 4);
        f4 wb0 = LD4(w1 + D_ + jj0), wb1 = LD4(w1 + D_ + jj0 + 4);
        f4 bb0 = LD4(b1 + jj0),      bb1 = LD4(b1 + jj0 + 4);
#pragma unroll
        for (int pp = 0; pp < 4; ++pp) {
            const float2 yv = *(const float2*)(y + 2 * (i0 + pp));
            f4 h0, h1;
            h0.x = fmaxf(fmaf(yv.y, wb0.x, fmaf(yv.x, wa0.x, bb0.x)), 0.f);
            h0.y = fmaxf(fmaf(yv.y, wb0.y, fmaf(yv.x, wa0.y, bb0.y)), 0.f);
            h0.z = fmaxf(fmaf(yv.y, wb0.z, fmaf(yv.x, wa0.z, bb0.z)), 0.f);
            h0.w = fmaxf(fmaf(yv.y, wb0.w, fmaf(yv.x, wa0.w, bb0.w)), 0.f);
            h1.x = fmaxf(fmaf(yv.y, wb1.x, fmaf(yv.x, wa1.x, bb1.x)), 0.f);
            h1.y = fmaxf(fmaf(yv.y, wb1.y, fmaf(yv.x, wa1.y, bb1.y)), 0.f);
            h1.z = fmaxf(fmaf(yv.y, wb1.z, fmaf(yv.x, wa1.z, bb1.z)), 0.f);
            h1.w = fmaxf(fmaf(yv.y, wb1.w, fmaf(yv.x, wa1.w, bb1.w)), 0.f);
            float* hp = h_lds + (g * 4 + pp) * PSTR + jj0;
            *(f4*)hp = h0; *(f4*)(hp + 4) = h1;
        }
    }
    __syncthreads();

    float o[4][8];
    {
        f4 b20 = LD4(b2 + jj0), b21 = LD4(b2 + jj0 + 4);
#pragma unroll
        for (int pp = 0; pp < 4; ++pp) {
            o[pp][0]=b20.x; o[pp][1]=b20.y; o[pp][2]=b20.z; o[pp][3]=b20.w;
            o[pp][4]=b21.x; o[pp][5]=b21.y; o[pp][6]=b21.z; o[pp][7]=b21.w;
        }
    }
#pragma unroll 2
    for (int k4 = 0; k4 < 16; ++k4) {
        const f4 x0 = LD4(h_lds + (g * 4 + 0) * PSTR + 4 * k4);
        const f4 x1 = LD4(h_lds + (g * 4 + 1) * PSTR + 4 * k4);
        const f4 x2 = LD4(h_lds + (g * 4 + 2) * PSTR + 4 * k4);
        const f4 x3 = LD4(h_lds + (g * 4 + 3) * PSTR + 4 * k4);
        const float* wk = w2s + (4 * k4) * D_ + jj0;
#pragma unroll
        for (int q = 0; q < 4; ++q) {
            const f4 wa = LD4(wk + q * D_), wb = LD4(wk + q * D_ + 4);
            fma8(o[0], f4c(x0, q), wa, wb);
            fma8(o[1], f4c(x1, q), wa, wb);
            fma8(o[2], f4c(x2, q), wa, wb);
            fma8(o[3], f4c(x3, q), wa, wb);
        }
    }

    const int sp0 = (((jj0 >> 2) & 3) << 4) | (((jj0 >> 4) & 3) << 2);
    const int sp1 = ((((jj0 + 4) >> 2) & 3) << 4) | ((((jj0 + 4) >> 4) & 3) << 2);
#pragma unroll
    for (int pp = 0; pp < 4; ++pp) {
        const size_t rb = (size_t)(i0 + pp) * D_;
        union { short s[8]; uint2 v[2]; } uh, ul;
#pragma unroll
        for (int q = 0; q < 8; ++q) splitbf(o[pp][q], uh.s[q], ul.s[q]);
        *(uint2*)(e_hi + rb + sp0) = uh.v[0];
        *(uint2*)(e_hi + rb + sp1) = uh.v[1];
        *(uint2*)(e_lo + rb + sp0) = ul.v[0];
        *(uint2*)(e_lo + rb + sp1) = ul.v[1];
    }
    if (s < 4) v_out[i0 + s] = x[i0 + s];
}

// ---------------------------------------------------------------------------
// Global tree stage (t = 0..4): r11-proven version. Full wblob in LDS,
// 512 thr = 8 waves x 32 pairs (both nets per wave).
// ---------------------------------------------------------------------------
__global__ __launch_bounds__(512, 2) void stage_kernel(
    const short* __restrict__ e_hi, const short* __restrict__ e_lo,
    const int* __restrict__ v_in,
    short* __restrict__ eo_hi, short* __restrict__ eo_lo, int* __restrict__ v_out,
    const short* __restrict__ wblob,
    const float* __restrict__ cn_b1, const float* __restrict__ cn_b2,
    const float* __restrict__ bn_b2, const float* __restrict__ contrib,
    const float* __restrict__ llr_w, const float* __restrict__ llr_b,
    float* __restrict__ loss_out, float2* __restrict__ pscr,
    int t, int log2Lh)
{
    __shared__ short wlds[WBLOB_SHORTS];   // 96 KB
    const int tid = threadIdx.x;
    {
        const uint4* src = (const uint4*)wblob;
        uint4* dst = (uint4*)wlds;
#pragma unroll
        for (int i = 0; i < 12; ++i)
            dst[tid + i * 512] = src[tid + i * 512];
    }
    __syncthreads();

    const int lane = tid & 63;
    const int pr = lane & 15, kg = lane >> 4;
    const int wid = tid >> 6;
    const int P0 = (blockIdx.x * 8 + wid) * 32;
    const int b  = P0 >> 11;
    const int Lh = 1 << log2Lh;

    int v1s[2], vx[2];
#pragma unroll
    for (int s = 0; s < 2; ++s) {
        const int gp = P0 + s * 16 + pr;
        const int2 vv = *(const int2*)(v_in + 2 * gp);
        v1s[s] = vv.y; vx[s] = (vv.x ^ vv.y) & 1;
    }

    f32x4 aC[2][4], aB[2][4];
#pragma unroll
    for (int mt = 0; mt < 4; ++mt) {
        const f4 bc = LD4(cn_b1 + mt * 16 + kg * 4);
#pragma unroll
        for (int s = 0; s < 2; ++s) {
            aC[s][mt] = (f32x4){bc.x, bc.y, bc.z, bc.w};
            const f4 cb = LD4(contrib + vx[s] * 64 + mt * 16 + kg * 4);
            aB[s][mt] = (f32x4){cb.x, cb.y, cb.z, cb.w};
        }
    }

#pragma unroll
    for (int kt = 0; kt < 4; ++kt) {
        short8 Eh[2], El[2];
#pragma unroll
        for (int s = 0; s < 2; ++s) {
            const size_t pos = (size_t)(2 * (P0 + s * 16 + pr) + (kt >> 1));
            const int off = (kt & 1) * 32 + kg * 8;
            Eh[s] = *(const short8*)(e_hi + pos * D_ + off);
            El[s] = *(const short8*)(e_lo + pos * D_ + off);
        }
#pragma unroll
        for (int mt = 0; mt < 4; ++mt) {
            const int fo = ((kt * 4 + mt) * 64 + lane) * 8;
            const short8 wh = *(const short8*)(wlds + OFF_C1H + fo);
            const short8 wl = *(const short8*)(wlds + OFF_C1L + fo);
            const short8 uh = *(const short8*)(wlds + OFF_B1H + fo);
            const short8 ul = *(const short8*)(wlds + OFF_B1L + fo);
#pragma unroll
            for (int s = 0; s < 2; ++s) {
                aC[s][mt] = MFMA(wh, Eh[s], aC[s][mt]);
                aC[s][mt] = MFMA(wl, Eh[s], aC[s][mt]);
                aC[s][mt] = MFMA(wh, El[s], aC[s][mt]);
                aB[s][mt] = MFMA(uh, Eh[s], aB[s][mt]);
                aB[s][mt] = MFMA(ul, Eh[s], aB[s][mt]);
                aB[s][mt] = MFMA(uh, El[s], aB[s][mt]);
            }
        }
    }

#pragma unroll
    for (int net = 0; net < 2; ++net) {
        const int w2h_off = net ? OFF_B2TH : OFF_C2TH;
        const int w2l_off = net ? OFF_B2TL : OFF_C2TL;
        const float* __restrict__ b2 = net ? bn_b2 : cn_b2;

        s4b hh[2][4], hl[2][4];
#pragma unroll
        for (int s = 0; s < 2; ++s)
#pragma unroll
            for (int ks = 0; ks < 4; ++ks) {
                const f32x4 a = net ? aB[s][ks] : aC[s][ks];
#pragma unroll
                for (int e2 = 0; e2 < 4; ++e2) {
                    short sh, sl2;
                    splitbf(fmaxf(a[e2], 0.f), sh, sl2);
                    hh[s][ks][e2] = sh; hl[s][ks][e2] = sl2;
                }
            }

        f32x4 o[2][4];
#pragma unroll
        for (int mt2 = 0; mt2 < 4; ++mt2) {
            const f4 bb = LD4(b2 + mt2 * 16 + kg * 4);
#pragma unroll
            for (int s = 0; s < 2; ++s) o[s][mt2] = (f32x4){bb.x, bb.y, bb.z, bb.w};
        }
#pragma unroll
        for (int ks = 0; ks < 4; ++ks)
#pragma unroll
            for (int mt2 = 0; mt2 < 4; ++mt2) {
                const int fo4 = ((ks * 4 + mt2) * 64 + lane) * 4;
                const s4b wh = *(const s4b*)(wlds + w2h_off + fo4);
                const s4b wl = *(const s4b*)(wlds + w2l_off + fo4);
#pragma unroll
                for (int s = 0; s < 2; ++s) {
                    o[s][mt2] = MFMA16(wh, hh[s][ks], o[s][mt2]);
                    o[s][mt2] = MFMA16(wl, hh[s][ks], o[s][mt2]);
                    o[s][mt2] = MFMA16(wh, hl[s][ks], o[s][mt2]);
                }
            }

#pragma unroll
        for (int s = 0; s < 2; ++s) {
            const int gp = P0 + s * 16 + pr;
            const int P  = gp & 2047;
            const int j  = P & (Lh - 1);
            const int io = 2 * P - j + (net ? Lh : 0);
            const int gout = b * N_ + io;

            float z0 = 0.f, z1 = 0.f;
#pragma unroll
            for (int mt2 = 0; mt2 < 4; ++mt2) {
                const int f0 = mt2 * 16 + kg * 4;
                const f4 wA = LD4(llr_w + 2 * f0);
                const f4 wB = LD4(llr_w + 2 * f0 + 4);
                z0 += o[s][mt2][0] * wA.x + o[s][mt2][1] * wA.z +
                      o[s][mt2][2] * wB.x + o[s][mt2][3] * wB.z;
                z1 += o[s][mt2][0] * wA.y + o[s][mt2][1] * wA.w +
                      o[s][mt2][2] * wB.y + o[s][mt2][3] * wB.w;
            }
            z0 += __shfl_xor(z0, 16); z1 += __shfl_xor(z1, 16);
            z0 += __shfl_xor(z0, 32); z1 += __shfl_xor(z1, 32);

            union { short sv[16]; uint4 v[2]; } ph, pl;
#pragma unroll
            for (int mt2 = 0; mt2 < 4; ++mt2)
#pragma unroll
                for (int e2 = 0; e2 < 4; ++e2) {
                    short sh, sl2;
                    splitbf(o[s][mt2][e2], sh, sl2);
                    ph.sv[mt2 * 4 + e2] = sh; pl.sv[mt2 * 4 + e2] = sl2;
                }
            const size_t eb = (size_t)gout * D_ + kg * 16;
            *(uint4*)(eo_hi + eb)     = ph.v[0];
            *(uint4*)(eo_hi + eb + 8) = ph.v[1];
            *(uint4*)(eo_lo + eb)     = pl.v[0];
            *(uint4*)(eo_lo + eb + 8) = pl.v[1];

            if (kg == 0) {
                v_out[gout] = net ? v1s[s] : vx[s];
                const float zz0 = z0 + llr_b[0], zz1 = z1 + llr_b[1];
                const float m   = fmaxf(zz0, zz1);
                const float ex0 = expf(zz0 - m), ex1 = expf(zz1 - m);
                const float inv = 1.0f / (ex0 + ex1);
                const float p0s = ex0 * inv, p1s = ex1 * inv;
                const float c0  = fminf(fmaxf(p0s, EPS_), 1.0f - EPS_);
                const float c1  = fminf(fmaxf(p1s, EPS_), 1.0f - EPS_);
                const int   lab = net ? (v1s[s] & 1) : vx[s];
                const float loss = -logf(lab ? c1 : c0);
                loss_out[(b * T_ + t) * N_ + io] = loss;
                pscr[(size_t)(b * T_ + t) * N_ + io] = make_float2(p0s, p1s);
            }
        }
    }
}

// ---------------------------------------------------------------------------
// Fused tail (t = 5..11): 512 thr = 8 waves = (net x sg0..3), 16 pairs/wave.
// LDS unchanged (72KB) -> 2 blocks/CU = 16 waves/CU = 4/SIMD. W1 loaded
// per-kt from global wblob (L2-hot), VGPR capped at 128 by launch_bounds.
// ---------------------------------------------------------------------------
__global__ __launch_bounds__(512, 4) void fused_tail(
    const short* __restrict__ e_hi, const short* __restrict__ e_lo,
    const int* __restrict__ v_in,
    const short* __restrict__ wblob,
    const float* __restrict__ cn_b1, const float* __restrict__ cn_b2,
    const float* __restrict__ bn_b2, const float* __restrict__ contrib,
    const float* __restrict__ llr_w, const float* __restrict__ llr_b,
    float* __restrict__ loss_out, float2* __restrict__ pscr)
{
    __shared__ __align__(16) short w2lds[16384];       // 32 KB
    __shared__ __align__(16) short ehl[2][128 * ESTR]; // 2 x 18KB hi/lo planes
    __shared__ int v_lds[128];
    __shared__ __align__(16) float cst[448];           // contrib|b1|b2c|b2b|llr
    const int tid = threadIdx.x;
    {
        uint4* dst = (uint4*)w2lds;
        const uint4* src = (const uint4*)(wblob + OFF_C2TH);
#pragma unroll
        for (int i = 0; i < 4; ++i)
            dst[tid + i * 512] = src[tid + i * 512];
    }
    if (tid < 128) { cst[tid] = contrib[tid]; cst[320 + tid] = llr_w[tid]; }
    if (tid < 64) {
        cst[128 + tid] = cn_b1[tid];
        cst[192 + tid] = cn_b2[tid];
        cst[256 + tid] = bn_b2[tid];
    }
    const int b = blockIdx.x >> 5, ch = blockIdx.x & 31;
    const int base_row = b * N_ + ch * 128;
    {
        const int r = tid >> 2, seg = tid & 3;           // 4 threads/row
        const size_t g = (size_t)(base_row + r) * D_ + seg * 16;
#pragma unroll
        for (int pl = 0; pl < 2; ++pl) {
            const short* sp = (pl ? e_lo : e_hi) + g;
            short* dp = &ehl[pl][r * ESTR + seg * 16];
            *(uint4*)dp       = *(const uint4*)sp;
            *(uint4*)(dp + 8) = *(const uint4*)(sp + 8);
        }
        if (tid < 128) v_lds[tid] = v_in[base_row + tid];
    }

    const int lane = tid & 63;
    const int pr = lane & 15, kg = lane >> 4;
    const int wid = tid >> 6;
    const int net = wid >> 2, sg = wid & 3;
    const int w2b = net * 8192;
    const short* __restrict__ w1hg = wblob + (net ? OFF_B1H : OFF_C1H);
    const short* __restrict__ w1lg = wblob + (net ? OFF_B1L : OFF_C1L);
    const float* b2c = net ? (cst + 256) : (cst + 192);
    __syncthreads();

    int Lh = 64;
#pragma unroll 1
    for (int t = 5; t < 12; ++t, Lh >>= 1) {
        const int p = sg * 16 + pr;
        const int v0 = v_lds[2 * p], v1 = v_lds[2 * p + 1];
        const int vx = (v0 ^ v1) & 1;

        f32x4 acc[4];
#pragma unroll
        for (int mt = 0; mt < 4; ++mt) {
            if (net) {
                const f4 cb = LD4(cst + vx * 64 + mt * 16 + kg * 4);
                acc[mt] = (f32x4){cb.x, cb.y, cb.z, cb.w};
            } else {
                const f4 bc = LD4(cst + 128 + mt * 16 + kg * 4);
                acc[mt] = (f32x4){bc.x, bc.y, bc.z, bc.w};
            }
        }

#pragma unroll
        for (int kt = 0; kt < 4; ++kt) {
            // prefetch this kt's W1 fragments (L2-hot)
            short8 wh0 = *(const short8*)(w1hg + ((kt * 4 + 0) * 64 + lane) * 8);
            short8 wl0 = *(const short8*)(w1lg + ((kt * 4 + 0) * 64 + lane) * 8);
            short8 wh1 = *(const short8*)(w1hg + ((kt * 4 + 1) * 64 + lane) * 8);
            short8 wl1 = *(const short8*)(w1lg + ((kt * 4 + 1) * 64 + lane) * 8);
            short8 wh2 = *(const short8*)(w1hg + ((kt * 4 + 2) * 64 + lane) * 8);
            short8 wl2 = *(const short8*)(w1lg + ((kt * 4 + 2) * 64 + lane) * 8);
            short8 wh3 = *(const short8*)(w1hg + ((kt * 4 + 3) * 64 + lane) * 8);
            short8 wl3 = *(const short8*)(w1lg + ((kt * 4 + 3) * 64 + lane) * 8);

            const int off = (2 * p + (kt >> 1)) * ESTR + (kt & 1) * 32 + kg * 8;
            const short8 Eh = *(const short8*)&ehl[0][off];
            const short8 El = *(const short8*)&ehl[1][off];

            acc[0] = MFMA(wh0, Eh, acc[0]);
            acc[0] = MFMA(wl0, Eh, acc[0]);
            acc[0] = MFMA(wh0, El, acc[0]);
            acc[1] = MFMA(wh1, Eh, acc[1]);
            acc[1] = MFMA(wl1, Eh, acc[1]);
            acc[1] = MFMA(wh1, El, acc[1]);
            acc[2] = MFMA(wh2, Eh, acc[2]);
            acc[2] = MFMA(wl2, Eh, acc[2]);
            acc[2] = MFMA(wh2, El, acc[2]);
            acc[3] = MFMA(wh3, Eh, acc[3]);
            acc[3] = MFMA(wl3, Eh, acc[3]);
            acc[3] = MFMA(wh3, El, acc[3]);
        }

        s4b hh[4], hl[4];
#pragma unroll
        for (int ks = 0; ks < 4; ++ks)
#pragma unroll
            for (int e2 = 0; e2 < 4; ++e2) {
                short sh, sl2;
                splitbf(fmaxf(acc[ks][e2], 0.f), sh, sl2);
                hh[ks][e2] = sh; hl[ks][e2] = sl2;
            }

        f32x4 o[4];
#pragma unroll
        for (int mt2 = 0; mt2 < 4; ++mt2) {
            const f4 bb = LD4(b2c + mt2 * 16 + kg * 4);
            o[mt2] = (f32x4){bb.x, bb.y, bb.z, bb.w};
        }
#pragma unroll
        for (int ks = 0; ks < 4; ++ks)
#pragma unroll
            for (int mt2 = 0; mt2 < 4; ++mt2) {
                const int fo4 = ((ks * 4 + mt2) * 64 + lane) * 4;
                const s4b wh = *(const s4b*)(w2lds + w2b + fo4);
                const s4b wl = *(const s4b*)(w2lds + w2b + 4096 + fo4);
                o[mt2] = MFMA16(wh, hh[ks], o[mt2]);
                o[mt2] = MFMA16(wl, hh[ks], o[mt2]);
                o[mt2] = MFMA16(wh, hl[ks], o[mt2]);
            }

        // ---- epilogue ----
        const int j = p & (Lh - 1);
        const int iol = 2 * p - j + (net ? Lh : 0);
        const int vnew = net ? v1 : vx;

        uint4 pkh[2], pkl[2];
        float z0 = 0.f, z1 = 0.f;
        {
            union { short sv[16]; uint4 v[2]; } ph, pl;
#pragma unroll
            for (int mt2 = 0; mt2 < 4; ++mt2) {
#pragma unroll
                for (int e2 = 0; e2 < 4; ++e2) {
                    short sh, sl2;
                    splitbf(o[mt2][e2], sh, sl2);
                    ph.sv[mt2 * 4 + e2] = sh; pl.sv[mt2 * 4 + e2] = sl2;
                }
                const int f0 = mt2 * 16 + kg * 4;
                const f4 wA = LD4(cst + 320 + 2 * f0);
                const f4 wB = LD4(cst + 320 + 2 * f0 + 4);
                z0 += o[mt2][0] * wA.x + o[mt2][1] * wA.z +
                      o[mt2][2] * wB.x + o[mt2][3] * wB.z;
                z1 += o[mt2][0] * wA.y + o[mt2][1] * wA.w +
                      o[mt2][2] * wB.y + o[mt2][3] * wB.w;
            }
            pkh[0] = ph.v[0]; pkh[1] = ph.v[1];
            pkl[0] = pl.v[0]; pkl[1] = pl.v[1];
        }
        z0 += __shfl_xor(z0, 16); z1 += __shfl_xor(z1, 16);
        z0 += __shfl_xor(z0, 32); z1 += __shfl_xor(z1, 32);

        if (kg == 0) {
            const int io = ch * 128 + iol;
            const float zz0 = z0 + llr_b[0], zz1 = z1 + llr_b[1];
            const float m   = fmaxf(zz0, zz1);
            const float ex0 = expf(zz0 - m), ex1 = expf(zz1 - m);
            const float inv = 1.0f / (ex0 + ex1);
            const float p0s = ex0 * inv, p1s = ex1 * inv;
            const float c0  = fminf(fmaxf(p0s, EPS_), 1.0f - EPS_);
            const float c1  = fminf(fmaxf(p1s, EPS_), 1.0f - EPS_);
            const int   lab = net ? (v1 & 1) : vx;
            const float loss = -logf(lab ? c1 : c0);
            loss_out[(b * T_ + t) * N_ + io] = loss;
            pscr[(size_t)(b * T_ + t) * N_ + io] = make_float2(p0s, p1s);
        }
        __syncthreads();   // all e/v reads of this stage complete

        {
            short* dh = &ehl[0][iol * ESTR + kg * 16];
            short* dl = &ehl[1][iol * ESTR + kg * 16];
            *(uint4*)dh       = pkh[0];
            *(uint4*)(dh + 8) = pkh[1];
            *(uint4*)dl       = pkl[0];
            *(uint4*)(dl + 8) = pkl[1];
            if (kg == 0) v_lds[iol] = vnew;
        }
        __syncthreads();   // writes visible for next stage
    }
}

// ---------------------------------------------------------------------------
// Final: transpose pscr [b][t][io](2) -> pred [b][io][t][2], both copies.
// ---------------------------------------------------------------------------
__global__ __launch_bounds__(256) void pred_epilogue(
    const float2* __restrict__ pscr,
    float* __restrict__ pred1, float* __restrict__ pred2)
{
    const int idx = blockIdx.x * 256 + threadIdx.x;   // b*N + io
    const int b = idx >> 12, io = idx & (N_ - 1);
    float2 v[T_];
#pragma unroll
    for (int t = 0; t < T_; ++t)
        v[t] = pscr[(size_t)(b * T_ + t) * N_ + io];
    float* d1 = pred1 + (size_t)idx * (T_ * 2);
    float* d2 = pred2 + (size_t)idx * (T_ * 2);
#pragma unroll
    for (int q = 0; q < 6; ++q) {
        const f4 w = make_float4(v[2 * q].x, v[2 * q].y, v[2 * q + 1].x, v[2 * q + 1].y);
        *(f4*)(d1 + 4 * q) = w;
        *(f4*)(d2 + 4 * q) = w;
    }
}

// ---------------------------------------------------------------------------
extern "C" void kernel_launch(void* const* d_in, const int* in_sizes, int n_in,
                              void* d_out, int out_size, void* d_ws, size_t ws_size,
                              hipStream_t stream)
{
    const int*   x      = (const int*)  d_in[0];
    const float* y      = (const float*)d_in[1];
    const float* emb_w1 = (const float*)d_in[2];
    const float* emb_b1 = (const float*)d_in[3];
    const float* emb_w2 = (const float*)d_in[4];
    const float* emb_b2 = (const float*)d_in[5];
    const float* cn_w1  = (const float*)d_in[6];
    const float* cn_b1  = (const float*)d_in[7];
    const float* cn_w2  = (const float*)d_in[8];
    const float* cn_b2  = (const float*)d_in[9];
    const float* bn_w1  = (const float*)d_in[10];
    const float* bn_b1  = (const float*)d_in[11];
    const float* bn_w2  = (const float*)d_in[12];
    const float* bn_b2  = (const float*)d_in[13];
    const float* llr_w  = (const float*)d_in[14];
    const float* llr_b  = (const float*)d_in[15];
    const float* label_emb = (const float*)d_in[16];

    float* out      = (float*)d_out;
    float* loss_out = out;
    float* pred1    = out + (size_t)B_ * T_ * N_;
    float* pred2    = pred1 + (size_t)B_ * N_ * T_ * 2;

    const size_t EPLANE = (size_t)B_ * N_ * D_;
    short* eh_a = (short*)d_ws;
    short* el_a = eh_a + EPLANE;
    short* eh_b = el_a + EPLANE;
    short* el_b = eh_b + EPLANE;
    int*   v_a  = (int*)(el_b + EPLANE);
    int*   v_b  = v_a + B_ * N_;
    float2* pscr = (float2*)(v_b + B_ * N_);
    short* wblob = (short*)(pscr + (size_t)B_ * T_ * N_);
    float* contrib = (float*)(wblob + WBLOB_SHORTS);

    prep_kernel<<<dim3(49), dim3(256), 0, stream>>>(
        cn_w1, cn_w2, bn_w1, bn_w2, bn_b1, label_emb, wblob, contrib);

    emb_kernel<<<dim3(B_ * N_ / 128), dim3(256), 0, stream>>>(
        x, y, emb_w1, emb_b1, emb_w2, emb_b2, eh_a, el_a, v_a);

    short* ehc = eh_a; short* elc = el_a; short* ehn = eh_b; short* eln = el_b;
    int* vc = v_a; int* vn = v_b;
    for (int t = 0; t < 5; ++t) {
        stage_kernel<<<dim3(B_ * N_ / 2 / 256), dim3(512), 0, stream>>>(
            ehc, elc, vc, ehn, eln, vn, wblob,
            cn_b1, cn_b2, bn_b2, contrib, llr_w, llr_b,
            loss_out, pscr, t, 11 - t);
        short* t1 = ehc; ehc = ehn; ehn = t1;
        short* t2 = elc; elc = eln; eln = t2;
        int* t3 = vc; vc = vn; vn = t3;
    }

    fused_tail<<<dim3(1024), dim3(512), 0, stream>>>(
        ehc, elc, vc, wblob,
        cn_b1, cn_b2, bn_b2, contrib, llr_w, llr_b,
        loss_out, pscr);

    pred_epilogue<<<dim3(B_ * N_ / 256), dim3(256), 0, stream>>>(
        pscr, pred1, pred2);
}

// Round 16
// 206.825 us; speedup vs baseline: 1.4340x; 1.4340x over previous
//
#include <hip/hip_runtime.h>
#include <math.h>

#define B_ 32
#define N_ 4096
#define D_ 64
#define T_ 12
#define EPS_ 1e-7f
#define PSTR 65
#define ESTR 72   // e-plane LDS row stride in SHORTS (144B, 16B-aligned)

typedef float4 f4;
#define LD4(p) (*(const float4*)(p))

typedef __attribute__((ext_vector_type(8))) short short8;
typedef __attribute__((ext_vector_type(4))) short s4b;
typedef __attribute__((ext_vector_type(4))) float f32x4;
#define MFMA(a, b, c)   __builtin_amdgcn_mfma_f32_16x16x32_bf16(a, b, c, 0, 0, 0)
#define MFMA16(a, b, c) __builtin_amdgcn_mfma_f32_16x16x16bf16_1k(a, b, c, 0, 0, 0)

// weight blob offsets (shorts) in global wblob
#define OFF_C1H 0
#define OFF_C1L 8192
#define OFF_B1H 16384
#define OFF_B1L 24576
#define OFF_C2TH 32768
#define OFF_C2TL 36864
#define OFF_B2TH 40960
#define OFF_B2TL 45056
#define WBLOB_SHORTS 49152

__device__ __forceinline__ float f4c(const float4 v, int q) {
    return q == 0 ? v.x : q == 1 ? v.y : q == 2 ? v.z : v.w;
}
__device__ __forceinline__ void fma8(float (&acc)[8], float a, const float4 w0, const float4 w1) {
    acc[0] = fmaf(a, w0.x, acc[0]); acc[1] = fmaf(a, w0.y, acc[1]);
    acc[2] = fmaf(a, w0.z, acc[2]); acc[3] = fmaf(a, w0.w, acc[3]);
    acc[4] = fmaf(a, w1.x, acc[4]); acc[5] = fmaf(a, w1.y, acc[5]);
    acc[6] = fmaf(a, w1.z, acc[6]); acc[7] = fmaf(a, w1.w, acc[7]);
}

__device__ __forceinline__ void splitbf(float a, short& h, short& l) {
    unsigned x = __float_as_uint(a);
    h = (short)(x >> 16);
    float r = a - __uint_as_float(x & 0xffff0000u);
    l = (short)(__float_as_uint(r) >> 16);
}

// sigma: involutive feature permutation for e-storage (swap bits[5:4]<->[3:2])
__device__ __forceinline__ int sigma_(int f) {
    return (((f >> 2) & 3) << 4) | (((f >> 4) & 3) << 2) | (f & 3);
}

// ---------------------------------------------------------------------------
// Prep (parallel): blocks 0-31 w1 packs, 32-47 w2^T packs, 48 contrib.
// ---------------------------------------------------------------------------
__global__ void prep_kernel(
    const float* __restrict__ cn_w1, const float* __restrict__ cn_w2,
    const float* __restrict__ bn_w1, const float* __restrict__ bn_w2,
    const float* __restrict__ bn_b1, const float* __restrict__ label_emb,
    short* __restrict__ wblob, float* __restrict__ contrib)
{
    const int bid = blockIdx.x, tid = threadIdx.x;
    if (bid < 32) {                                  // w1 packs (K=128)
        const int idx = bid * 256 + tid;
        const int e = idx & 7, l = (idx >> 3) & 63, fb = idx >> 9;
        const int kt = fb >> 2, mt = fb & 3;
        const int f_lin = (kt & 1) * 32 + (l >> 4) * 8 + e;
        const int k = (kt >> 1) * 64 + sigma_(f_lin);
        const int n = mt * 16 + (l & 15);
        short h, lo;
        splitbf(cn_w1[k * 64 + n], h, lo);
        wblob[OFF_C1H + idx] = h; wblob[OFF_C1L + idx] = lo;
        splitbf(bn_w1[k * 64 + n], h, lo);
        wblob[OFF_B1H + idx] = h; wblob[OFF_B1L + idx] = lo;
    } else if (bid < 48) {                           // w2^T packs (16x16x16 A)
        const int idx = (bid - 32) * 256 + tid;
        const int e = idx & 3, l = (idx >> 2) & 63, fb = idx >> 8;
        const int ks = fb >> 2, mt2 = fb & 3;
        const int k = ks * 16 + (l >> 4) * 4 + e;
        const int n = mt2 * 16 + (l & 15);
        short h, lo;
        splitbf(cn_w2[k * 64 + n], h, lo);
        wblob[OFF_C2TH + idx] = h; wblob[OFF_C2TL + idx] = lo;
        splitbf(bn_w2[k * 64 + n], h, lo);
        wblob[OFF_B2TH + idx] = h; wblob[OFF_B2TL + idx] = lo;
    } else if (tid < 128) {                          // contrib
        const int c = tid >> 6, n = tid & 63;
        float s = bn_b1[n];
#pragma unroll 8
        for (int kk = 0; kk < 64; ++kk)
            s = fmaf(label_emb[c * 64 + kk], bn_w1[(128 + kk) * 64 + n], s);
        contrib[c * 64 + n] = s;
    }
}

// ---------------------------------------------------------------------------
// Embedding (fp32 vector, w2 staged in LDS). Writes e planes in sigma order.
// ---------------------------------------------------------------------------
__global__ __launch_bounds__(256, 3) void emb_kernel(
    const int* __restrict__ x, const float* __restrict__ y,
    const float* __restrict__ w1, const float* __restrict__ b1,
    const float* __restrict__ w2, const float* __restrict__ b2,
    short* __restrict__ e_hi, short* __restrict__ e_lo, int* __restrict__ v_out)
{
    __shared__ float h_lds[128 * PSTR];
    __shared__ __align__(16) float w2s[4096];   // 16 KB
    const int tid = threadIdx.x;
    const int s   = tid & 7;
    const int g   = tid >> 3;
    const int jj0 = s * 8;
    const int i0  = (blockIdx.x * 32 + g) * 4;

    {   // stage w2 into LDS (covered by the barrier below)
        float4* d = (float4*)w2s;
        const float4* sp = (const float4*)w2;
#pragma unroll
        for (int i = 0; i < 4; ++i)
            d[tid + i * 256] = sp[tid + i * 256];
    }

    {
        f4 wa0 = LD4(w1 + jj0),      wa1 = LD4(w1 + jj0 + 4);
        f4 wb0 = LD4(w1 + D_ + jj0), wb1 = LD4(w1 + D_ + jj0 + 4);
        f4 bb0 = LD4(b1 + jj0),      bb1 = LD4(b1 + jj0 + 4);
#pragma unroll
        for (int pp = 0; pp < 4; ++pp) {
            const float2 yv = *(const float2*)(y + 2 * (i0 + pp));
            f4 h0, h1;
            h0.x = fmaxf(fmaf(yv.y, wb0.x, fmaf(yv.x, wa0.x, bb0.x)), 0.f);
            h0.y = fmaxf(fmaf(yv.y, wb0.y, fmaf(yv.x, wa0.y, bb0.y)), 0.f);
            h0.z = fmaxf(fmaf(yv.y, wb0.z, fmaf(yv.x, wa0.z, bb0.z)), 0.f);
            h0.w = fmaxf(fmaf(yv.y, wb0.w, fmaf(yv.x, wa0.w, bb0.w)), 0.f);
            h1.x = fmaxf(fmaf(yv.y, wb1.x, fmaf(yv.x, wa1.x, bb1.x)), 0.f);
            h1.y = fmaxf(fmaf(yv.y, wb1.y, fmaf(yv.x, wa1.y, bb1.y)), 0.f);
            h1.z = fmaxf(fmaf(yv.y, wb1.z, fmaf(yv.x, wa1.z, bb1.z)), 0.f);
            h1.w = fmaxf(fmaf(yv.y, wb1.w, fmaf(yv.x, wa1.w, bb1.w)), 0.f);
            float* hp = h_lds + (g * 4 + pp) * PSTR + jj0;
            *(f4*)hp = h0; *(f4*)(hp + 4) = h1;
        }
    }
    __syncthreads();

    float o[4][8];
    {
        f4 b20 = LD4(b2 + jj0), b21 = LD4(b2 + jj0 + 4);
#pragma unroll
        for (int pp = 0; pp < 4; ++pp) {
            o[pp][0]=b20.x; o[pp][1]=b20.y; o[pp][2]=b20.z; o[pp][3]=b20.w;
            o[pp][4]=b21.x; o[pp][5]=b21.y; o[pp][6]=b21.z; o[pp][7]=b21.w;
        }
    }
#pragma unroll 2
    for (int k4 = 0; k4 < 16; ++k4) {
        const f4 x0 = LD4(h_lds + (g * 4 + 0) * PSTR + 4 * k4);
        const f4 x1 = LD4(h_lds + (g * 4 + 1) * PSTR + 4 * k4);
        const f4 x2 = LD4(h_lds + (g * 4 + 2) * PSTR + 4 * k4);
        const f4 x3 = LD4(h_lds + (g * 4 + 3) * PSTR + 4 * k4);
        const float* wk = w2s + (4 * k4) * D_ + jj0;
#pragma unroll
        for (int q = 0; q < 4; ++q) {
            const f4 wa = LD4(wk + q * D_), wb = LD4(wk + q * D_ + 4);
            fma8(o[0], f4c(x0, q), wa, wb);
            fma8(o[1], f4c(x1, q), wa, wb);
            fma8(o[2], f4c(x2, q), wa, wb);
            fma8(o[3], f4c(x3, q), wa, wb);
        }
    }

    const int sp0 = (((jj0 >> 2) & 3) << 4) | (((jj0 >> 4) & 3) << 2);
    const int sp1 = ((((jj0 + 4) >> 2) & 3) << 4) | ((((jj0 + 4) >> 4) & 3) << 2);
#pragma unroll
    for (int pp = 0; pp < 4; ++pp) {
        const size_t rb = (size_t)(i0 + pp) * D_;
        union { short s[8]; uint2 v[2]; } uh, ul;
#pragma unroll
        for (int q = 0; q < 8; ++q) splitbf(o[pp][q], uh.s[q], ul.s[q]);
        *(uint2*)(e_hi + rb + sp0) = uh.v[0];
        *(uint2*)(e_hi + rb + sp1) = uh.v[1];
        *(uint2*)(e_lo + rb + sp0) = ul.v[0];
        *(uint2*)(e_lo + rb + sp1) = ul.v[1];
    }
    if (s < 4) v_out[i0 + s] = x[i0 + s];
}

// ---------------------------------------------------------------------------
// Global tree stage (t = 0..4): r11-proven version. Full wblob in LDS,
// 512 thr = 8 waves x 32 pairs (both nets per wave).
// ---------------------------------------------------------------------------
__global__ __launch_bounds__(512, 2) void stage_kernel(
    const short* __restrict__ e_hi, const short* __restrict__ e_lo,
    const int* __restrict__ v_in,
    short* __restrict__ eo_hi, short* __restrict__ eo_lo, int* __restrict__ v_out,
    const short* __restrict__ wblob,
    const float* __restrict__ cn_b1, const float* __restrict__ cn_b2,
    const float* __restrict__ bn_b2, const float* __restrict__ contrib,
    const float* __restrict__ llr_w, const float* __restrict__ llr_b,
    float* __restrict__ loss_out, float2* __restrict__ pscr,
    int t, int log2Lh)
{
    __shared__ short wlds[WBLOB_SHORTS];   // 96 KB
    const int tid = threadIdx.x;
    {
        const uint4* src = (const uint4*)wblob;
        uint4* dst = (uint4*)wlds;
#pragma unroll
        for (int i = 0; i < 12; ++i)
            dst[tid + i * 512] = src[tid + i * 512];
    }
    __syncthreads();

    const int lane = tid & 63;
    const int pr = lane & 15, kg = lane >> 4;
    const int wid = tid >> 6;
    const int P0 = (blockIdx.x * 8 + wid) * 32;
    const int b  = P0 >> 11;
    const int Lh = 1 << log2Lh;

    int v1s[2], vx[2];
#pragma unroll
    for (int s = 0; s < 2; ++s) {
        const int gp = P0 + s * 16 + pr;
        const int2 vv = *(const int2*)(v_in + 2 * gp);
        v1s[s] = vv.y; vx[s] = (vv.x ^ vv.y) & 1;
    }

    f32x4 aC[2][4], aB[2][4];
#pragma unroll
    for (int mt = 0; mt < 4; ++mt) {
        const f4 bc = LD4(cn_b1 + mt * 16 + kg * 4);
#pragma unroll
        for (int s = 0; s < 2; ++s) {
            aC[s][mt] = (f32x4){bc.x, bc.y, bc.z, bc.w};
            const f4 cb = LD4(contrib + vx[s] * 64 + mt * 16 + kg * 4);
            aB[s][mt] = (f32x4){cb.x, cb.y, cb.z, cb.w};
        }
    }

#pragma unroll
    for (int kt = 0; kt < 4; ++kt) {
        short8 Eh[2], El[2];
#pragma unroll
        for (int s = 0; s < 2; ++s) {
            const size_t pos = (size_t)(2 * (P0 + s * 16 + pr) + (kt >> 1));
            const int off = (kt & 1) * 32 + kg * 8;
            Eh[s] = *(const short8*)(e_hi + pos * D_ + off);
            El[s] = *(const short8*)(e_lo + pos * D_ + off);
        }
#pragma unroll
        for (int mt = 0; mt < 4; ++mt) {
            const int fo = ((kt * 4 + mt) * 64 + lane) * 8;
            const short8 wh = *(const short8*)(wlds + OFF_C1H + fo);
            const short8 wl = *(const short8*)(wlds + OFF_C1L + fo);
            const short8 uh = *(const short8*)(wlds + OFF_B1H + fo);
            const short8 ul = *(const short8*)(wlds + OFF_B1L + fo);
#pragma unroll
            for (int s = 0; s < 2; ++s) {
                aC[s][mt] = MFMA(wh, Eh[s], aC[s][mt]);
                aC[s][mt] = MFMA(wl, Eh[s], aC[s][mt]);
                aC[s][mt] = MFMA(wh, El[s], aC[s][mt]);
                aB[s][mt] = MFMA(uh, Eh[s], aB[s][mt]);
                aB[s][mt] = MFMA(ul, Eh[s], aB[s][mt]);
                aB[s][mt] = MFMA(uh, El[s], aB[s][mt]);
            }
        }
    }

#pragma unroll
    for (int net = 0; net < 2; ++net) {
        const int w2h_off = net ? OFF_B2TH : OFF_C2TH;
        const int w2l_off = net ? OFF_B2TL : OFF_C2TL;
        const float* __restrict__ b2 = net ? bn_b2 : cn_b2;

        s4b hh[2][4], hl[2][4];
#pragma unroll
        for (int s = 0; s < 2; ++s)
#pragma unroll
            for (int ks = 0; ks < 4; ++ks) {
                const f32x4 a = net ? aB[s][ks] : aC[s][ks];
#pragma unroll
                for (int e2 = 0; e2 < 4; ++e2) {
                    short sh, sl2;
                    splitbf(fmaxf(a[e2], 0.f), sh, sl2);
                    hh[s][ks][e2] = sh; hl[s][ks][e2] = sl2;
                }
            }

        f32x4 o[2][4];
#pragma unroll
        for (int mt2 = 0; mt2 < 4; ++mt2) {
            const f4 bb = LD4(b2 + mt2 * 16 + kg * 4);
#pragma unroll
            for (int s = 0; s < 2; ++s) o[s][mt2] = (f32x4){bb.x, bb.y, bb.z, bb.w};
        }
#pragma unroll
        for (int ks = 0; ks < 4; ++ks)
#pragma unroll
            for (int mt2 = 0; mt2 < 4; ++mt2) {
                const int fo4 = ((ks * 4 + mt2) * 64 + lane) * 4;
                const s4b wh = *(const s4b*)(wlds + w2h_off + fo4);
                const s4b wl = *(const s4b*)(wlds + w2l_off + fo4);
#pragma unroll
                for (int s = 0; s < 2; ++s) {
                    o[s][mt2] = MFMA16(wh, hh[s][ks], o[s][mt2]);
                    o[s][mt2] = MFMA16(wl, hh[s][ks], o[s][mt2]);
                    o[s][mt2] = MFMA16(wh, hl[s][ks], o[s][mt2]);
                }
            }

#pragma unroll
        for (int s = 0; s < 2; ++s) {
            const int gp = P0 + s * 16 + pr;
            const int P  = gp & 2047;
            const int j  = P & (Lh - 1);
            const int io = 2 * P - j + (net ? Lh : 0);
            const int gout = b * N_ + io;

            float z0 = 0.f, z1 = 0.f;
#pragma unroll
            for (int mt2 = 0; mt2 < 4; ++mt2) {
                const int f0 = mt2 * 16 + kg * 4;
                const f4 wA = LD4(llr_w + 2 * f0);
                const f4 wB = LD4(llr_w + 2 * f0 + 4);
                z0 += o[s][mt2][0] * wA.x + o[s][mt2][1] * wA.z +
                      o[s][mt2][2] * wB.x + o[s][mt2][3] * wB.z;
                z1 += o[s][mt2][0] * wA.y + o[s][mt2][1] * wA.w +
                      o[s][mt2][2] * wB.y + o[s][mt2][3] * wB.w;
            }
            z0 += __shfl_xor(z0, 16); z1 += __shfl_xor(z1, 16);
            z0 += __shfl_xor(z0, 32); z1 += __shfl_xor(z1, 32);

            union { short sv[16]; uint4 v[2]; } ph, pl;
#pragma unroll
            for (int mt2 = 0; mt2 < 4; ++mt2)
#pragma unroll
                for (int e2 = 0; e2 < 4; ++e2) {
                    short sh, sl2;
                    splitbf(o[s][mt2][e2], sh, sl2);
                    ph.sv[mt2 * 4 + e2] = sh; pl.sv[mt2 * 4 + e2] = sl2;
                }
            const size_t eb = (size_t)gout * D_ + kg * 16;
            *(uint4*)(eo_hi + eb)     = ph.v[0];
            *(uint4*)(eo_hi + eb + 8) = ph.v[1];
            *(uint4*)(eo_lo + eb)     = pl.v[0];
            *(uint4*)(eo_lo + eb + 8) = pl.v[1];

            if (kg == 0) {
                v_out[gout] = net ? v1s[s] : vx[s];
                const float zz0 = z0 + llr_b[0], zz1 = z1 + llr_b[1];
                const float m   = fmaxf(zz0, zz1);
                const float ex0 = expf(zz0 - m), ex1 = expf(zz1 - m);
                const float inv = 1.0f / (ex0 + ex1);
                const float p0s = ex0 * inv, p1s = ex1 * inv;
                const float c0  = fminf(fmaxf(p0s, EPS_), 1.0f - EPS_);
                const float c1  = fminf(fmaxf(p1s, EPS_), 1.0f - EPS_);
                const int   lab = net ? (v1s[s] & 1) : vx[s];
                const float loss = -logf(lab ? c1 : c0);
                loss_out[(b * T_ + t) * N_ + io] = loss;
                pscr[(size_t)(b * T_ + t) * N_ + io] = make_float2(p0s, p1s);
            }
        }
    }
}

// ---------------------------------------------------------------------------
// Fused tail (t = 5..11): r14-proven version (W1 in regs, 256 thr, 72 KB LDS,
// 2 blocks/CU) + folded pred transpose epilogue at the end.
// ---------------------------------------------------------------------------
__global__ __launch_bounds__(256, 2) void fused_tail(
    const short* __restrict__ e_hi, const short* __restrict__ e_lo,
    const int* __restrict__ v_in,
    const short* __restrict__ wblob,
    const float* __restrict__ cn_b1, const float* __restrict__ cn_b2,
    const float* __restrict__ bn_b2, const float* __restrict__ contrib,
    const float* __restrict__ llr_w, const float* __restrict__ llr_b,
    float* __restrict__ loss_out, float2* __restrict__ pscr,
    float* __restrict__ pred1, float* __restrict__ pred2)
{
    __shared__ __align__(16) short w2lds[16384];       // 32 KB
    __shared__ __align__(16) short ehl[2][128 * ESTR]; // 2 x 18KB hi/lo planes
    __shared__ int v_lds[128];
    __shared__ __align__(16) float cst[448];           // contrib|b1|b2c|b2b|llr
    const int tid = threadIdx.x;
    {
        uint4* dst = (uint4*)w2lds;
        const uint4* src = (const uint4*)(wblob + OFF_C2TH);
#pragma unroll
        for (int i = 0; i < 8; ++i)
            dst[tid + i * 256] = src[tid + i * 256];
    }
    if (tid < 128) { cst[tid] = contrib[tid]; cst[320 + tid] = llr_w[tid]; }
    if (tid < 64) {
        cst[128 + tid] = cn_b1[tid];
        cst[192 + tid] = cn_b2[tid];
        cst[256 + tid] = bn_b2[tid];
    }
    const int b = blockIdx.x >> 5, ch = blockIdx.x & 31;
    const int base_row = b * N_ + ch * 128;
    {
        const int r = tid >> 1, seg = tid & 1;
        const size_t g = (size_t)(base_row + r) * D_ + seg * 32;
#pragma unroll
        for (int pl = 0; pl < 2; ++pl) {
            const short* sp = (pl ? e_lo : e_hi) + g;
            short* dp = &ehl[pl][r * ESTR + seg * 32];
            *(uint4*)dp        = *(const uint4*)sp;
            *(uint4*)(dp + 8)  = *(const uint4*)(sp + 8);
            *(uint4*)(dp + 16) = *(const uint4*)(sp + 16);
            *(uint4*)(dp + 24) = *(const uint4*)(sp + 24);
        }
        if (tid < 128) v_lds[tid] = v_in[base_row + tid];
    }

    const int lane = tid & 63;
    const int pr = lane & 15, kg = lane >> 4;
    const int wid = tid >> 6;
    const int net = wid >> 1, sg = wid & 1;
    const int w2b = net * 8192;

    short8 w1h[16], w1l[16];
    {
        const short* wh = wblob + (net ? OFF_B1H : OFF_C1H);
        const short* wl = wblob + (net ? OFF_B1L : OFF_C1L);
#pragma unroll
        for (int f = 0; f < 16; ++f) {
            const int fo = (f * 64 + lane) * 8;
            w1h[f] = *(const short8*)(wh + fo);
            w1l[f] = *(const short8*)(wl + fo);
        }
    }
    const float* b2c = net ? (cst + 256) : (cst + 192);
    __syncthreads();

    int Lh = 64;
#pragma unroll 1
    for (int t = 5; t < 12; ++t, Lh >>= 1) {
        int pA[2], v1A[2], vxA[2];
        f32x4 acc[2][4];
#pragma unroll
        for (int s = 0; s < 2; ++s) {
            const int p = sg * 32 + s * 16 + pr;
            pA[s] = p;
            const int v0 = v_lds[2 * p], v1 = v_lds[2 * p + 1];
            v1A[s] = v1; vxA[s] = (v0 ^ v1) & 1;
#pragma unroll
            for (int mt = 0; mt < 4; ++mt) {
                if (net) {
                    const f4 cb = LD4(cst + vxA[s] * 64 + mt * 16 + kg * 4);
                    acc[s][mt] = (f32x4){cb.x, cb.y, cb.z, cb.w};
                } else {
                    const f4 bc = LD4(cst + 128 + mt * 16 + kg * 4);
                    acc[s][mt] = (f32x4){bc.x, bc.y, bc.z, bc.w};
                }
            }
        }

#pragma unroll
        for (int kt = 0; kt < 4; ++kt) {
            short8 Eh[2], El[2];
#pragma unroll
            for (int s = 0; s < 2; ++s) {
                const int off = (2 * pA[s] + (kt >> 1)) * ESTR + (kt & 1) * 32 + kg * 8;
                Eh[s] = *(const short8*)&ehl[0][off];
                El[s] = *(const short8*)&ehl[1][off];
            }
#pragma unroll
            for (int mt = 0; mt < 4; ++mt) {
                const short8 wh = w1h[kt * 4 + mt], wl = w1l[kt * 4 + mt];
#pragma unroll
                for (int s = 0; s < 2; ++s) {
                    acc[s][mt] = MFMA(wh, Eh[s], acc[s][mt]);
                    acc[s][mt] = MFMA(wl, Eh[s], acc[s][mt]);
                    acc[s][mt] = MFMA(wh, El[s], acc[s][mt]);
                }
            }
        }

        s4b hh[2][4], hl[2][4];
#pragma unroll
        for (int s = 0; s < 2; ++s)
#pragma unroll
            for (int ks = 0; ks < 4; ++ks)
#pragma unroll
                for (int e2 = 0; e2 < 4; ++e2) {
                    short sh, sl2;
                    splitbf(fmaxf(acc[s][ks][e2], 0.f), sh, sl2);
                    hh[s][ks][e2] = sh; hl[s][ks][e2] = sl2;
                }

        f32x4 o[2][4];
#pragma unroll
        for (int mt2 = 0; mt2 < 4; ++mt2) {
            const f4 bb = LD4(b2c + mt2 * 16 + kg * 4);
#pragma unroll
            for (int s = 0; s < 2; ++s) o[s][mt2] = (f32x4){bb.x, bb.y, bb.z, bb.w};
        }
#pragma unroll
        for (int ks = 0; ks < 4; ++ks)
#pragma unroll
            for (int mt2 = 0; mt2 < 4; ++mt2) {
                const int fo4 = ((ks * 4 + mt2) * 64 + lane) * 4;
                const s4b wh = *(const s4b*)(w2lds + w2b + fo4);
                const s4b wl = *(const s4b*)(w2lds + w2b + 4096 + fo4);
#pragma unroll
                for (int s = 0; s < 2; ++s) {
                    o[s][mt2] = MFMA16(wh, hh[s][ks], o[s][mt2]);
                    o[s][mt2] = MFMA16(wl, hh[s][ks], o[s][mt2]);
                    o[s][mt2] = MFMA16(wh, hl[s][ks], o[s][mt2]);
                }
            }

        int iolA[2], vnA[2];
        uint4 pkh[2][2], pkl[2][2];
#pragma unroll
        for (int s = 0; s < 2; ++s) {
            const int p = pA[s];
            const int j = p & (Lh - 1);
            const int iol = 2 * p - j + (net ? Lh : 0);
            iolA[s] = iol;
            vnA[s]  = net ? v1A[s] : vxA[s];

            float z0 = 0.f, z1 = 0.f;
            union { short sv[16]; uint4 v[2]; } ph, pl;
#pragma unroll
            for (int mt2 = 0; mt2 < 4; ++mt2) {
#pragma unroll
                for (int e2 = 0; e2 < 4; ++e2) {
                    short sh, sl2;
                    splitbf(o[s][mt2][e2], sh, sl2);
                    ph.sv[mt2 * 4 + e2] = sh; pl.sv[mt2 * 4 + e2] = sl2;
                }
                const int f0 = mt2 * 16 + kg * 4;
                const f4 wA = LD4(cst + 320 + 2 * f0);
                const f4 wB = LD4(cst + 320 + 2 * f0 + 4);
                z0 += o[s][mt2][0] * wA.x + o[s][mt2][1] * wA.z +
                      o[s][mt2][2] * wB.x + o[s][mt2][3] * wB.z;
                z1 += o[s][mt2][0] * wA.y + o[s][mt2][1] * wA.w +
                      o[s][mt2][2] * wB.y + o[s][mt2][3] * wB.w;
            }
            pkh[s][0] = ph.v[0]; pkh[s][1] = ph.v[1];
            pkl[s][0] = pl.v[0]; pkl[s][1] = pl.v[1];
            z0 += __shfl_xor(z0, 16); z1 += __shfl_xor(z1, 16);
            z0 += __shfl_xor(z0, 32); z1 += __shfl_xor(z1, 32);

            if (kg == 0) {
                const int io = ch * 128 + iol;
                const float zz0 = z0 + llr_b[0], zz1 = z1 + llr_b[1];
                const float m   = fmaxf(zz0, zz1);
                const float ex0 = expf(zz0 - m), ex1 = expf(zz1 - m);
                const float inv = 1.0f / (ex0 + ex1);
                const float p0s = ex0 * inv, p1s = ex1 * inv;
                const float c0  = fminf(fmaxf(p0s, EPS_), 1.0f - EPS_);
                const float c1  = fminf(fmaxf(p1s, EPS_), 1.0f - EPS_);
                const int   lab = net ? (v1A[s] & 1) : vxA[s];
                const float loss = -logf(lab ? c1 : c0);
                loss_out[(b * T_ + t) * N_ + io] = loss;
                pscr[(size_t)(b * T_ + t) * N_ + io] = make_float2(p0s, p1s);
            }
        }
        __syncthreads();   // all e/v reads of this stage complete

#pragma unroll
        for (int s = 0; s < 2; ++s) {
            short* dh = &ehl[0][iolA[s] * ESTR + kg * 16];
            short* dl = &ehl[1][iolA[s] * ESTR + kg * 16];
            *(uint4*)dh       = pkh[s][0];
            *(uint4*)(dh + 8) = pkh[s][1];
            *(uint4*)dl       = pkl[s][0];
            *(uint4*)(dl + 8) = pkl[s][1];
            if (kg == 0) v_lds[iolA[s]] = vnA[s];
        }
        __syncthreads();   // writes visible for next stage
    }

    // ---- folded pred transpose: this block's 128 positions ----
    // t=0..4 written by prior kernels; t=5..11 by this block (visible after
    // the barrier above per block-level global coherence).
    if (tid < 128) {
        const int io  = ch * 128 + tid;
        const int idx = b * N_ + io;
        float2 v[T_];
#pragma unroll
        for (int t = 0; t < T_; ++t)
            v[t] = pscr[(size_t)(b * T_ + t) * N_ + io];
        float* d1 = pred1 + (size_t)idx * (T_ * 2);
        float* d2 = pred2 + (size_t)idx * (T_ * 2);
#pragma unroll
        for (int q = 0; q < 6; ++q) {
            const f4 w = make_float4(v[2 * q].x, v[2 * q].y, v[2 * q + 1].x, v[2 * q + 1].y);
            *(f4*)(d1 + 4 * q) = w;
            *(f4*)(d2 + 4 * q) = w;
        }
    }
}

// ---------------------------------------------------------------------------
extern "C" void kernel_launch(void* const* d_in, const int* in_sizes, int n_in,
                              void* d_out, int out_size, void* d_ws, size_t ws_size,
                              hipStream_t stream)
{
    const int*   x      = (const int*)  d_in[0];
    const float* y      = (const float*)d_in[1];
    const float* emb_w1 = (const float*)d_in[2];
    const float* emb_b1 = (const float*)d_in[3];
    const float* emb_w2 = (const float*)d_in[4];
    const float* emb_b2 = (const float*)d_in[5];
    const float* cn_w1  = (const float*)d_in[6];
    const float* cn_b1  = (const float*)d_in[7];
    const float* cn_w2  = (const float*)d_in[8];
    const float* cn_b2  = (const float*)d_in[9];
    const float* bn_w1  = (const float*)d_in[10];
    const float* bn_b1  = (const float*)d_in[11];
    const float* bn_w2  = (const float*)d_in[12];
    const float* bn_b2  = (const float*)d_in[13];
    const float* llr_w  = (const float*)d_in[14];
    const float* llr_b  = (const float*)d_in[15];
    const float* label_emb = (const float*)d_in[16];

    float* out      = (float*)d_out;
    float* loss_out = out;
    float* pred1    = out + (size_t)B_ * T_ * N_;
    float* pred2    = pred1 + (size_t)B_ * N_ * T_ * 2;

    const size_t EPLANE = (size_t)B_ * N_ * D_;
    short* eh_a = (short*)d_ws;
    short* el_a = eh_a + EPLANE;
    short* eh_b = el_a + EPLANE;
    short* el_b = eh_b + EPLANE;
    int*   v_a  = (int*)(el_b + EPLANE);
    int*   v_b  = v_a + B_ * N_;
    float2* pscr = (float2*)(v_b + B_ * N_);
    short* wblob = (short*)(pscr + (size_t)B_ * T_ * N_);
    float* contrib = (float*)(wblob + WBLOB_SHORTS);

    prep_kernel<<<dim3(49), dim3(256), 0, stream>>>(
        cn_w1, cn_w2, bn_w1, bn_w2, bn_b1, label_emb, wblob, contrib);

    emb_kernel<<<dim3(B_ * N_ / 128), dim3(256), 0, stream>>>(
        x, y, emb_w1, emb_b1, emb_w2, emb_b2, eh_a, el_a, v_a);

    short* ehc = eh_a; short* elc = el_a; short* ehn = eh_b; short* eln = el_b;
    int* vc = v_a; int* vn = v_b;
    for (int t = 0; t < 5; ++t) {
        stage_kernel<<<dim3(B_ * N_ / 2 / 256), dim3(512), 0, stream>>>(
            ehc, elc, vc, ehn, eln, vn, wblob,
            cn_b1, cn_b2, bn_b2, contrib, llr_w, llr_b,
            loss_out, pscr, t, 11 - t);
        short* t1 = ehc; ehc = ehn; ehn = t1;
        short* t2 = elc; elc = eln; eln = t2;
        int* t3 = vc; vc = vn; vn = t3;
    }

    fused_tail<<<dim3(1024), dim3(256), 0, stream>>>(
        ehc, elc, vc, wblob,
        cn_b1, cn_b2, bn_b2, contrib, llr_w, llr_b,
        loss_out, pscr, pred1, pred2);
}

// Round 17
// 189.295 us; speedup vs baseline: 1.5668x; 1.0926x over previous
//
#include <hip/hip_runtime.h>
#include <math.h>

#define B_ 32
#define N_ 4096
#define D_ 64
#define T_ 12
#define EPS_ 1e-7f
#define PSTR 65
#define ESTR 72   // e-plane LDS row stride in SHORTS (144B, 16B-aligned)

typedef float4 f4;
#define LD4(p) (*(const float4*)(p))

typedef __attribute__((ext_vector_type(8))) short short8;
typedef __attribute__((ext_vector_type(4))) short s4b;
typedef __attribute__((ext_vector_type(4))) float f32x4;
#define MFMA(a, b, c)   __builtin_amdgcn_mfma_f32_16x16x32_bf16(a, b, c, 0, 0, 0)
#define MFMA16(a, b, c) __builtin_amdgcn_mfma_f32_16x16x16bf16_1k(a, b, c, 0, 0, 0)

// weight blob offsets (shorts) in global wblob
#define OFF_C1H 0
#define OFF_C1L 8192
#define OFF_B1H 16384
#define OFF_B1L 24576
#define OFF_C2TH 32768
#define OFF_C2TL 36864
#define OFF_B2TH 40960
#define OFF_B2TL 45056
#define WBLOB_SHORTS 49152

__device__ __forceinline__ float f4c(const float4 v, int q) {
    return q == 0 ? v.x : q == 1 ? v.y : q == 2 ? v.z : v.w;
}
__device__ __forceinline__ void fma8(float (&acc)[8], float a, const float4 w0, const float4 w1) {
    acc[0] = fmaf(a, w0.x, acc[0]); acc[1] = fmaf(a, w0.y, acc[1]);
    acc[2] = fmaf(a, w0.z, acc[2]); acc[3] = fmaf(a, w0.w, acc[3]);
    acc[4] = fmaf(a, w1.x, acc[4]); acc[5] = fmaf(a, w1.y, acc[5]);
    acc[6] = fmaf(a, w1.z, acc[6]); acc[7] = fmaf(a, w1.w, acc[7]);
}

__device__ __forceinline__ void splitbf(float a, short& h, short& l) {
    unsigned x = __float_as_uint(a);
    h = (short)(x >> 16);
    float r = a - __uint_as_float(x & 0xffff0000u);
    l = (short)(__float_as_uint(r) >> 16);
}

// sigma: involutive feature permutation for e-storage (swap bits[5:4]<->[3:2])
__device__ __forceinline__ int sigma_(int f) {
    return (((f >> 2) & 3) << 4) | (((f >> 4) & 3) << 2) | (f & 3);
}

// ---------------------------------------------------------------------------
// Prep (parallel): blocks 0-31 w1 packs, 32-47 w2^T packs, 48 contrib.
// ---------------------------------------------------------------------------
__global__ void prep_kernel(
    const float* __restrict__ cn_w1, const float* __restrict__ cn_w2,
    const float* __restrict__ bn_w1, const float* __restrict__ bn_w2,
    const float* __restrict__ bn_b1, const float* __restrict__ label_emb,
    short* __restrict__ wblob, float* __restrict__ contrib)
{
    const int bid = blockIdx.x, tid = threadIdx.x;
    if (bid < 32) {                                  // w1 packs (K=128)
        const int idx = bid * 256 + tid;
        const int e = idx & 7, l = (idx >> 3) & 63, fb = idx >> 9;
        const int kt = fb >> 2, mt = fb & 3;
        const int f_lin = (kt & 1) * 32 + (l >> 4) * 8 + e;
        const int k = (kt >> 1) * 64 + sigma_(f_lin);
        const int n = mt * 16 + (l & 15);
        short h, lo;
        splitbf(cn_w1[k * 64 + n], h, lo);
        wblob[OFF_C1H + idx] = h; wblob[OFF_C1L + idx] = lo;
        splitbf(bn_w1[k * 64 + n], h, lo);
        wblob[OFF_B1H + idx] = h; wblob[OFF_B1L + idx] = lo;
    } else if (bid < 48) {                           // w2^T packs (16x16x16 A)
        const int idx = (bid - 32) * 256 + tid;
        const int e = idx & 3, l = (idx >> 2) & 63, fb = idx >> 8;
        const int ks = fb >> 2, mt2 = fb & 3;
        const int k = ks * 16 + (l >> 4) * 4 + e;
        const int n = mt2 * 16 + (l & 15);
        short h, lo;
        splitbf(cn_w2[k * 64 + n], h, lo);
        wblob[OFF_C2TH + idx] = h; wblob[OFF_C2TL + idx] = lo;
        splitbf(bn_w2[k * 64 + n], h, lo);
        wblob[OFF_B2TH + idx] = h; wblob[OFF_B2TL + idx] = lo;
    } else if (tid < 128) {                          // contrib
        const int c = tid >> 6, n = tid & 63;
        float s = bn_b1[n];
#pragma unroll 8
        for (int kk = 0; kk < 64; ++kk)
            s = fmaf(label_emb[c * 64 + kk], bn_w1[(128 + kk) * 64 + n], s);
        contrib[c * 64 + n] = s;
    }
}

// ---------------------------------------------------------------------------
// Embedding (fp32 vector, w2 staged in LDS). Writes e planes in sigma order.
// ---------------------------------------------------------------------------
__global__ __launch_bounds__(256, 3) void emb_kernel(
    const int* __restrict__ x, const float* __restrict__ y,
    const float* __restrict__ w1, const float* __restrict__ b1,
    const float* __restrict__ w2, const float* __restrict__ b2,
    short* __restrict__ e_hi, short* __restrict__ e_lo, int* __restrict__ v_out)
{
    __shared__ float h_lds[128 * PSTR];
    __shared__ __align__(16) float w2s[4096];   // 16 KB
    const int tid = threadIdx.x;
    const int s   = tid & 7;
    const int g   = tid >> 3;
    const int jj0 = s * 8;
    const int i0  = (blockIdx.x * 32 + g) * 4;

    {   // stage w2 into LDS (covered by the barrier below)
        float4* d = (float4*)w2s;
        const float4* sp = (const float4*)w2;
#pragma unroll
        for (int i = 0; i < 4; ++i)
            d[tid + i * 256] = sp[tid + i * 256];
    }

    {
        f4 wa0 = LD4(w1 + jj0),      wa1 = LD4(w1 + jj0 + 4);
        f4 wb0 = LD4(w1 + D_ + jj0), wb1 = LD4(w1 + D_ + jj0 + 4);
        f4 bb0 = LD4(b1 + jj0),      bb1 = LD4(b1 + jj0 + 4);
#pragma unroll
        for (int pp = 0; pp < 4; ++pp) {
            const float2 yv = *(const float2*)(y + 2 * (i0 + pp));
            f4 h0, h1;
            h0.x = fmaxf(fmaf(yv.y, wb0.x, fmaf(yv.x, wa0.x, bb0.x)), 0.f);
            h0.y = fmaxf(fmaf(yv.y, wb0.y, fmaf(yv.x, wa0.y, bb0.y)), 0.f);
            h0.z = fmaxf(fmaf(yv.y, wb0.z, fmaf(yv.x, wa0.z, bb0.z)), 0.f);
            h0.w = fmaxf(fmaf(yv.y, wb0.w, fmaf(yv.x, wa0.w, bb0.w)), 0.f);
            h1.x = fmaxf(fmaf(yv.y, wb1.x, fmaf(yv.x, wa1.x, bb1.x)), 0.f);
            h1.y = fmaxf(fmaf(yv.y, wb1.y, fmaf(yv.x, wa1.y, bb1.y)), 0.f);
            h1.z = fmaxf(fmaf(yv.y, wb1.z, fmaf(yv.x, wa1.z, bb1.z)), 0.f);
            h1.w = fmaxf(fmaf(yv.y, wb1.w, fmaf(yv.x, wa1.w, bb1.w)), 0.f);
            float* hp = h_lds + (g * 4 + pp) * PSTR + jj0;
            *(f4*)hp = h0; *(f4*)(hp + 4) = h1;
        }
    }
    __syncthreads();

    float o[4][8];
    {
        f4 b20 = LD4(b2 + jj0), b21 = LD4(b2 + jj0 + 4);
#pragma unroll
        for (int pp = 0; pp < 4; ++pp) {
            o[pp][0]=b20.x; o[pp][1]=b20.y; o[pp][2]=b20.z; o[pp][3]=b20.w;
            o[pp][4]=b21.x; o[pp][5]=b21.y; o[pp][6]=b21.z; o[pp][7]=b21.w;
        }
    }
#pragma unroll 2
    for (int k4 = 0; k4 < 16; ++k4) {
        const f4 x0 = LD4(h_lds + (g * 4 + 0) * PSTR + 4 * k4);
        const f4 x1 = LD4(h_lds + (g * 4 + 1) * PSTR + 4 * k4);
        const f4 x2 = LD4(h_lds + (g * 4 + 2) * PSTR + 4 * k4);
        const f4 x3 = LD4(h_lds + (g * 4 + 3) * PSTR + 4 * k4);
        const float* wk = w2s + (4 * k4) * D_ + jj0;
#pragma unroll
        for (int q = 0; q < 4; ++q) {
            const f4 wa = LD4(wk + q * D_), wb = LD4(wk + q * D_ + 4);
            fma8(o[0], f4c(x0, q), wa, wb);
            fma8(o[1], f4c(x1, q), wa, wb);
            fma8(o[2], f4c(x2, q), wa, wb);
            fma8(o[3], f4c(x3, q), wa, wb);
        }
    }

    const int sp0 = (((jj0 >> 2) & 3) << 4) | (((jj0 >> 4) & 3) << 2);
    const int sp1 = ((((jj0 + 4) >> 2) & 3) << 4) | ((((jj0 + 4) >> 4) & 3) << 2);
#pragma unroll
    for (int pp = 0; pp < 4; ++pp) {
        const size_t rb = (size_t)(i0 + pp) * D_;
        union { short s[8]; uint2 v[2]; } uh, ul;
#pragma unroll
        for (int q = 0; q < 8; ++q) splitbf(o[pp][q], uh.s[q], ul.s[q]);
        *(uint2*)(e_hi + rb + sp0) = uh.v[0];
        *(uint2*)(e_hi + rb + sp1) = uh.v[1];
        *(uint2*)(e_lo + rb + sp0) = ul.v[0];
        *(uint2*)(e_lo + rb + sp1) = ul.v[1];
    }
    if (s < 4) v_out[i0 + s] = x[i0 + s];
}

// ---------------------------------------------------------------------------
// Global tree stage (single, t=4): r11-proven version. Full wblob in LDS,
// 512 thr = 8 waves x 32 pairs (both nets per wave).
// ---------------------------------------------------------------------------
__global__ __launch_bounds__(512, 2) void stage_kernel(
    const short* __restrict__ e_hi, const short* __restrict__ e_lo,
    const int* __restrict__ v_in,
    short* __restrict__ eo_hi, short* __restrict__ eo_lo, int* __restrict__ v_out,
    const short* __restrict__ wblob,
    const float* __restrict__ cn_b1, const float* __restrict__ cn_b2,
    const float* __restrict__ bn_b2, const float* __restrict__ contrib,
    const float* __restrict__ llr_w, const float* __restrict__ llr_b,
    float* __restrict__ loss_out, float2* __restrict__ pscr,
    int t, int log2Lh)
{
    __shared__ short wlds[WBLOB_SHORTS];   // 96 KB
    const int tid = threadIdx.x;
    {
        const uint4* src = (const uint4*)wblob;
        uint4* dst = (uint4*)wlds;
#pragma unroll
        for (int i = 0; i < 12; ++i)
            dst[tid + i * 512] = src[tid + i * 512];
    }
    __syncthreads();

    const int lane = tid & 63;
    const int pr = lane & 15, kg = lane >> 4;
    const int wid = tid >> 6;
    const int P0 = (blockIdx.x * 8 + wid) * 32;
    const int b  = P0 >> 11;
    const int Lh = 1 << log2Lh;

    int v1s[2], vx[2];
#pragma unroll
    for (int s = 0; s < 2; ++s) {
        const int gp = P0 + s * 16 + pr;
        const int2 vv = *(const int2*)(v_in + 2 * gp);
        v1s[s] = vv.y; vx[s] = (vv.x ^ vv.y) & 1;
    }

    f32x4 aC[2][4], aB[2][4];
#pragma unroll
    for (int mt = 0; mt < 4; ++mt) {
        const f4 bc = LD4(cn_b1 + mt * 16 + kg * 4);
#pragma unroll
        for (int s = 0; s < 2; ++s) {
            aC[s][mt] = (f32x4){bc.x, bc.y, bc.z, bc.w};
            const f4 cb = LD4(contrib + vx[s] * 64 + mt * 16 + kg * 4);
            aB[s][mt] = (f32x4){cb.x, cb.y, cb.z, cb.w};
        }
    }

#pragma unroll
    for (int kt = 0; kt < 4; ++kt) {
        short8 Eh[2], El[2];
#pragma unroll
        for (int s = 0; s < 2; ++s) {
            const size_t pos = (size_t)(2 * (P0 + s * 16 + pr) + (kt >> 1));
            const int off = (kt & 1) * 32 + kg * 8;
            Eh[s] = *(const short8*)(e_hi + pos * D_ + off);
            El[s] = *(const short8*)(e_lo + pos * D_ + off);
        }
#pragma unroll
        for (int mt = 0; mt < 4; ++mt) {
            const int fo = ((kt * 4 + mt) * 64 + lane) * 8;
            const short8 wh = *(const short8*)(wlds + OFF_C1H + fo);
            const short8 wl = *(const short8*)(wlds + OFF_C1L + fo);
            const short8 uh = *(const short8*)(wlds + OFF_B1H + fo);
            const short8 ul = *(const short8*)(wlds + OFF_B1L + fo);
#pragma unroll
            for (int s = 0; s < 2; ++s) {
                aC[s][mt] = MFMA(wh, Eh[s], aC[s][mt]);
                aC[s][mt] = MFMA(wl, Eh[s], aC[s][mt]);
                aC[s][mt] = MFMA(wh, El[s], aC[s][mt]);
                aB[s][mt] = MFMA(uh, Eh[s], aB[s][mt]);
                aB[s][mt] = MFMA(ul, Eh[s], aB[s][mt]);
                aB[s][mt] = MFMA(uh, El[s], aB[s][mt]);
            }
        }
    }

#pragma unroll
    for (int net = 0; net < 2; ++net) {
        const int w2h_off = net ? OFF_B2TH : OFF_C2TH;
        const int w2l_off = net ? OFF_B2TL : OFF_C2TL;
        const float* __restrict__ b2 = net ? bn_b2 : cn_b2;

        s4b hh[2][4], hl[2][4];
#pragma unroll
        for (int s = 0; s < 2; ++s)
#pragma unroll
            for (int ks = 0; ks < 4; ++ks) {
                const f32x4 a = net ? aB[s][ks] : aC[s][ks];
#pragma unroll
                for (int e2 = 0; e2 < 4; ++e2) {
                    short sh, sl2;
                    splitbf(fmaxf(a[e2], 0.f), sh, sl2);
                    hh[s][ks][e2] = sh; hl[s][ks][e2] = sl2;
                }
            }

        f32x4 o[2][4];
#pragma unroll
        for (int mt2 = 0; mt2 < 4; ++mt2) {
            const f4 bb = LD4(b2 + mt2 * 16 + kg * 4);
#pragma unroll
            for (int s = 0; s < 2; ++s) o[s][mt2] = (f32x4){bb.x, bb.y, bb.z, bb.w};
        }
#pragma unroll
        for (int ks = 0; ks < 4; ++ks)
#pragma unroll
            for (int mt2 = 0; mt2 < 4; ++mt2) {
                const int fo4 = ((ks * 4 + mt2) * 64 + lane) * 4;
                const s4b wh = *(const s4b*)(wlds + w2h_off + fo4);
                const s4b wl = *(const s4b*)(wlds + w2l_off + fo4);
#pragma unroll
                for (int s = 0; s < 2; ++s) {
                    o[s][mt2] = MFMA16(wh, hh[s][ks], o[s][mt2]);
                    o[s][mt2] = MFMA16(wl, hh[s][ks], o[s][mt2]);
                    o[s][mt2] = MFMA16(wh, hl[s][ks], o[s][mt2]);
                }
            }

#pragma unroll
        for (int s = 0; s < 2; ++s) {
            const int gp = P0 + s * 16 + pr;
            const int P  = gp & 2047;
            const int j  = P & (Lh - 1);
            const int io = 2 * P - j + (net ? Lh : 0);
            const int gout = b * N_ + io;

            float z0 = 0.f, z1 = 0.f;
#pragma unroll
            for (int mt2 = 0; mt2 < 4; ++mt2) {
                const int f0 = mt2 * 16 + kg * 4;
                const f4 wA = LD4(llr_w + 2 * f0);
                const f4 wB = LD4(llr_w + 2 * f0 + 4);
                z0 += o[s][mt2][0] * wA.x + o[s][mt2][1] * wA.z +
                      o[s][mt2][2] * wB.x + o[s][mt2][3] * wB.z;
                z1 += o[s][mt2][0] * wA.y + o[s][mt2][1] * wA.w +
                      o[s][mt2][2] * wB.y + o[s][mt2][3] * wB.w;
            }
            z0 += __shfl_xor(z0, 16); z1 += __shfl_xor(z1, 16);
            z0 += __shfl_xor(z0, 32); z1 += __shfl_xor(z1, 32);

            union { short sv[16]; uint4 v[2]; } ph, pl;
#pragma unroll
            for (int mt2 = 0; mt2 < 4; ++mt2)
#pragma unroll
                for (int e2 = 0; e2 < 4; ++e2) {
                    short sh, sl2;
                    splitbf(o[s][mt2][e2], sh, sl2);
                    ph.sv[mt2 * 4 + e2] = sh; pl.sv[mt2 * 4 + e2] = sl2;
                }
            const size_t eb = (size_t)gout * D_ + kg * 16;
            *(uint4*)(eo_hi + eb)     = ph.v[0];
            *(uint4*)(eo_hi + eb + 8) = ph.v[1];
            *(uint4*)(eo_lo + eb)     = pl.v[0];
            *(uint4*)(eo_lo + eb + 8) = pl.v[1];

            if (kg == 0) {
                v_out[gout] = net ? v1s[s] : vx[s];
                const float zz0 = z0 + llr_b[0], zz1 = z1 + llr_b[1];
                const float m   = fmaxf(zz0, zz1);
                const float ex0 = expf(zz0 - m), ex1 = expf(zz1 - m);
                const float inv = 1.0f / (ex0 + ex1);
                const float p0s = ex0 * inv, p1s = ex1 * inv;
                const float c0  = fminf(fmaxf(p0s, EPS_), 1.0f - EPS_);
                const float c1  = fminf(fmaxf(p1s, EPS_), 1.0f - EPS_);
                const int   lab = net ? (v1s[s] & 1) : vx[s];
                const float loss = -logf(lab ? c1 : c0);
                loss_out[(b * T_ + t) * N_ + io] = loss;
                pscr[(size_t)(b * T_ + t) * N_ + io] = make_float2(p0s, p1s);
            }
        }
    }
}

// ---------------------------------------------------------------------------
// Fused EARLY pair of stages (t, t+1), Lh_t >= 128: block owns 64 stage-t
// pairs; intermediates live in LDS (cn run [C0..C0+63] -> rows 0..63, bn run
// [C0+Lh..] -> rows 64..127); stage t+1 consumes them locally. fused_tail
// template: W1-in-regs per net-wave, W2+cst in LDS, 256 thr, 2 blocks/CU.
// ---------------------------------------------------------------------------
__global__ __launch_bounds__(256, 2) void fused_early(
    const short* __restrict__ e_hi, const short* __restrict__ e_lo,
    const int* __restrict__ v_in,
    short* __restrict__ eo_hi, short* __restrict__ eo_lo, int* __restrict__ v_out,
    const short* __restrict__ wblob,
    const float* __restrict__ cn_b1, const float* __restrict__ cn_b2,
    const float* __restrict__ bn_b2, const float* __restrict__ contrib,
    const float* __restrict__ llr_w, const float* __restrict__ llr_b,
    float* __restrict__ loss_out, float2* __restrict__ pscr,
    int t, int log2Lh)
{
    __shared__ __align__(16) short w2lds[16384];       // 32 KB
    __shared__ __align__(16) short ehl[2][128 * ESTR]; // intermediates
    __shared__ int v_lds[128];
    __shared__ __align__(16) float cst[448];
    const int tid = threadIdx.x;
    {
        uint4* dst = (uint4*)w2lds;
        const uint4* src = (const uint4*)(wblob + OFF_C2TH);
#pragma unroll
        for (int i = 0; i < 8; ++i)
            dst[tid + i * 256] = src[tid + i * 256];
    }
    if (tid < 128) { cst[tid] = contrib[tid]; cst[320 + tid] = llr_w[tid]; }
    if (tid < 64) {
        cst[128 + tid] = cn_b1[tid];
        cst[192 + tid] = cn_b2[tid];
        cst[256 + tid] = bn_b2[tid];
    }

    const int lane = tid & 63;
    const int pr = lane & 15, kg = lane >> 4;
    const int wid = tid >> 6;
    const int net = wid >> 1, sg = wid & 1;
    const int w2b = net * 8192;
    const int P0  = blockIdx.x * 64;       // first stage-t global pair
    const int b   = P0 >> 11;
    const int Pb0 = P0 & 2047;
    const int Lh  = 1 << log2Lh;
    const int C0  = 2 * Pb0 - (Pb0 & (Lh - 1));   // cn run base (in-batch)

    short8 w1h[16], w1l[16];
    {
        const short* wh = wblob + (net ? OFF_B1H : OFF_C1H);
        const short* wl = wblob + (net ? OFF_B1L : OFF_C1L);
#pragma unroll
        for (int f = 0; f < 16; ++f) {
            const int fo = (f * 64 + lane) * 8;
            w1h[f] = *(const short8*)(wh + fo);
            w1l[f] = *(const short8*)(wl + fo);
        }
    }
    const float* b2c = net ? (cst + 256) : (cst + 192);
    __syncthreads();

    // ======== stage t: global e -> LDS intermediates ========
    {
        int dA[2], v1A[2], vxA[2];
        f32x4 acc[2][4];
#pragma unroll
        for (int s = 0; s < 2; ++s) {
            const int d = sg * 32 + s * 16 + pr;
            dA[s] = d;
            const int2 vv = *(const int2*)(v_in + 2 * (P0 + d));
            v1A[s] = vv.y; vxA[s] = (vv.x ^ vv.y) & 1;
#pragma unroll
            for (int mt = 0; mt < 4; ++mt) {
                if (net) {
                    const f4 cb = LD4(cst + vxA[s] * 64 + mt * 16 + kg * 4);
                    acc[s][mt] = (f32x4){cb.x, cb.y, cb.z, cb.w};
                } else {
                    const f4 bc = LD4(cst + 128 + mt * 16 + kg * 4);
                    acc[s][mt] = (f32x4){bc.x, bc.y, bc.z, bc.w};
                }
            }
        }

#pragma unroll
        for (int kt = 0; kt < 4; ++kt) {
            short8 Eh[2], El[2];
#pragma unroll
            for (int s = 0; s < 2; ++s) {
                const size_t pos = (size_t)(2 * (P0 + dA[s]) + (kt >> 1));
                const int off = (kt & 1) * 32 + kg * 8;
                Eh[s] = *(const short8*)(e_hi + pos * D_ + off);
                El[s] = *(const short8*)(e_lo + pos * D_ + off);
            }
#pragma unroll
            for (int mt = 0; mt < 4; ++mt) {
                const short8 wh = w1h[kt * 4 + mt], wl = w1l[kt * 4 + mt];
#pragma unroll
                for (int s = 0; s < 2; ++s) {
                    acc[s][mt] = MFMA(wh, Eh[s], acc[s][mt]);
                    acc[s][mt] = MFMA(wl, Eh[s], acc[s][mt]);
                    acc[s][mt] = MFMA(wh, El[s], acc[s][mt]);
                }
            }
        }

        s4b hh[2][4], hl[2][4];
#pragma unroll
        for (int s = 0; s < 2; ++s)
#pragma unroll
            for (int ks = 0; ks < 4; ++ks)
#pragma unroll
                for (int e2 = 0; e2 < 4; ++e2) {
                    short sh, sl2;
                    splitbf(fmaxf(acc[s][ks][e2], 0.f), sh, sl2);
                    hh[s][ks][e2] = sh; hl[s][ks][e2] = sl2;
                }

        f32x4 o[2][4];
#pragma unroll
        for (int mt2 = 0; mt2 < 4; ++mt2) {
            const f4 bb = LD4(b2c + mt2 * 16 + kg * 4);
#pragma unroll
            for (int s = 0; s < 2; ++s) o[s][mt2] = (f32x4){bb.x, bb.y, bb.z, bb.w};
        }
#pragma unroll
        for (int ks = 0; ks < 4; ++ks)
#pragma unroll
            for (int mt2 = 0; mt2 < 4; ++mt2) {
                const int fo4 = ((ks * 4 + mt2) * 64 + lane) * 4;
                const s4b wh = *(const s4b*)(w2lds + w2b + fo4);
                const s4b wl = *(const s4b*)(w2lds + w2b + 4096 + fo4);
#pragma unroll
                for (int s = 0; s < 2; ++s) {
                    o[s][mt2] = MFMA16(wh, hh[s][ks], o[s][mt2]);
                    o[s][mt2] = MFMA16(wl, hh[s][ks], o[s][mt2]);
                    o[s][mt2] = MFMA16(wh, hl[s][ks], o[s][mt2]);
                }
            }

#pragma unroll
        for (int s = 0; s < 2; ++s) {
            const int d    = dA[s];
            const int iloc = d + net * 64;

            float z0 = 0.f, z1 = 0.f;
            union { short sv[16]; uint4 v[2]; } ph, pl;
#pragma unroll
            for (int mt2 = 0; mt2 < 4; ++mt2) {
#pragma unroll
                for (int e2 = 0; e2 < 4; ++e2) {
                    short sh, sl2;
                    splitbf(o[s][mt2][e2], sh, sl2);
                    ph.sv[mt2 * 4 + e2] = sh; pl.sv[mt2 * 4 + e2] = sl2;
                }
                const int f0 = mt2 * 16 + kg * 4;
                const f4 wA = LD4(cst + 320 + 2 * f0);
                const f4 wB = LD4(cst + 320 + 2 * f0 + 4);
                z0 += o[s][mt2][0] * wA.x + o[s][mt2][1] * wA.z +
                      o[s][mt2][2] * wB.x + o[s][mt2][3] * wB.z;
                z1 += o[s][mt2][0] * wA.y + o[s][mt2][1] * wA.w +
                      o[s][mt2][2] * wB.y + o[s][mt2][3] * wB.w;
            }
            // intermediate -> LDS (fresh buffer; no pre-write barrier needed)
            short* dh = &ehl[0][iloc * ESTR + kg * 16];
            short* dl = &ehl[1][iloc * ESTR + kg * 16];
            *(uint4*)dh       = ph.v[0];
            *(uint4*)(dh + 8) = ph.v[1];
            *(uint4*)dl       = pl.v[0];
            *(uint4*)(dl + 8) = pl.v[1];

            z0 += __shfl_xor(z0, 16); z1 += __shfl_xor(z1, 16);
            z0 += __shfl_xor(z0, 32); z1 += __shfl_xor(z1, 32);

            if (kg == 0) {
                v_lds[iloc] = net ? v1A[s] : vxA[s];
                const int io = C0 + d + net * Lh;
                const float zz0 = z0 + llr_b[0], zz1 = z1 + llr_b[1];
                const float m   = fmaxf(zz0, zz1);
                const float ex0 = expf(zz0 - m), ex1 = expf(zz1 - m);
                const float inv = 1.0f / (ex0 + ex1);
                const float p0s = ex0 * inv, p1s = ex1 * inv;
                const float c0  = fminf(fmaxf(p0s, EPS_), 1.0f - EPS_);
                const float c1  = fminf(fmaxf(p1s, EPS_), 1.0f - EPS_);
                const int   lab = net ? (v1A[s] & 1) : vxA[s];
                const float loss = -logf(lab ? c1 : c0);
                loss_out[(b * T_ + t) * N_ + io] = loss;
                pscr[(size_t)(b * T_ + t) * N_ + io] = make_float2(p0s, p1s);
            }
        }
    }
    __syncthreads();

    // ======== stage t+1: LDS -> global ========
    {
        const int Lh2   = Lh >> 1;
        const int Q0    = (sg ? (C0 + Lh) : C0) >> 1;  // in-batch pair base
        const int rbase = sg * 64;                     // local row base

        int qlA[2], v1A[2], vxA[2];
        f32x4 acc[2][4];
#pragma unroll
        for (int s = 0; s < 2; ++s) {
            const int ql = s * 16 + pr;
            qlA[s] = ql;
            const int v0 = v_lds[rbase + 2 * ql], v1 = v_lds[rbase + 2 * ql + 1];
            v1A[s] = v1; vxA[s] = (v0 ^ v1) & 1;
#pragma unroll
            for (int mt = 0; mt < 4; ++mt) {
                if (net) {
                    const f4 cb = LD4(cst + vxA[s] * 64 + mt * 16 + kg * 4);
                    acc[s][mt] = (f32x4){cb.x, cb.y, cb.z, cb.w};
                } else {
                    const f4 bc = LD4(cst + 128 + mt * 16 + kg * 4);
                    acc[s][mt] = (f32x4){bc.x, bc.y, bc.z, bc.w};
                }
            }
        }

#pragma unroll
        for (int kt = 0; kt < 4; ++kt) {
            short8 Eh[2], El[2];
#pragma unroll
            for (int s = 0; s < 2; ++s) {
                const int off = (rbase + 2 * qlA[s] + (kt >> 1)) * ESTR + (kt & 1) * 32 + kg * 8;
                Eh[s] = *(const short8*)&ehl[0][off];
                El[s] = *(const short8*)&ehl[1][off];
            }
#pragma unroll
            for (int mt = 0; mt < 4; ++mt) {
                const short8 wh = w1h[kt * 4 + mt], wl = w1l[kt * 4 + mt];
#pragma unroll
                for (int s = 0; s < 2; ++s) {
                    acc[s][mt] = MFMA(wh, Eh[s], acc[s][mt]);
                    acc[s][mt] = MFMA(wl, Eh[s], acc[s][mt]);
                    acc[s][mt] = MFMA(wh, El[s], acc[s][mt]);
                }
            }
        }

        s4b hh[2][4], hl[2][4];
#pragma unroll
        for (int s = 0; s < 2; ++s)
#pragma unroll
            for (int ks = 0; ks < 4; ++ks)
#pragma unroll
                for (int e2 = 0; e2 < 4; ++e2) {
                    short sh, sl2;
                    splitbf(fmaxf(acc[s][ks][e2], 0.f), sh, sl2);
                    hh[s][ks][e2] = sh; hl[s][ks][e2] = sl2;
                }

        f32x4 o[2][4];
#pragma unroll
        for (int mt2 = 0; mt2 < 4; ++mt2) {
            const f4 bb = LD4(b2c + mt2 * 16 + kg * 4);
#pragma unroll
            for (int s = 0; s < 2; ++s) o[s][mt2] = (f32x4){bb.x, bb.y, bb.z, bb.w};
        }
#pragma unroll
        for (int ks = 0; ks < 4; ++ks)
#pragma unroll
            for (int mt2 = 0; mt2 < 4; ++mt2) {
                const int fo4 = ((ks * 4 + mt2) * 64 + lane) * 4;
                const s4b wh = *(const s4b*)(w2lds + w2b + fo4);
                const s4b wl = *(const s4b*)(w2lds + w2b + 4096 + fo4);
#pragma unroll
                for (int s = 0; s < 2; ++s) {
                    o[s][mt2] = MFMA16(wh, hh[s][ks], o[s][mt2]);
                    o[s][mt2] = MFMA16(wl, hh[s][ks], o[s][mt2]);
                    o[s][mt2] = MFMA16(wh, hl[s][ks], o[s][mt2]);
                }
            }

#pragma unroll
        for (int s = 0; s < 2; ++s) {
            const int Q   = Q0 + qlA[s];
            const int j2  = Q & (Lh2 - 1);
            const int io2 = 2 * Q - j2 + (net ? Lh2 : 0);
            const int gout = b * N_ + io2;

            float z0 = 0.f, z1 = 0.f;
            union { short sv[16]; uint4 v[2]; } ph, pl;
#pragma unroll
            for (int mt2 = 0; mt2 < 4; ++mt2) {
#pragma unroll
                for (int e2 = 0; e2 < 4; ++e2) {
                    short sh, sl2;
                    splitbf(o[s][mt2][e2], sh, sl2);
                    ph.sv[mt2 * 4 + e2] = sh; pl.sv[mt2 * 4 + e2] = sl2;
                }
                const int f0 = mt2 * 16 + kg * 4;
                const f4 wA = LD4(cst + 320 + 2 * f0);
                const f4 wB = LD4(cst + 320 + 2 * f0 + 4);
                z0 += o[s][mt2][0] * wA.x + o[s][mt2][1] * wA.z +
                      o[s][mt2][2] * wB.x + o[s][mt2][3] * wB.z;
                z1 += o[s][mt2][0] * wA.y + o[s][mt2][1] * wA.w +
                      o[s][mt2][2] * wB.y + o[s][mt2][3] * wB.w;
            }
            const size_t eb = (size_t)gout * D_ + kg * 16;
            *(uint4*)(eo_hi + eb)     = ph.v[0];
            *(uint4*)(eo_hi + eb + 8) = ph.v[1];
            *(uint4*)(eo_lo + eb)     = pl.v[0];
            *(uint4*)(eo_lo + eb + 8) = pl.v[1];

            z0 += __shfl_xor(z0, 16); z1 += __shfl_xor(z1, 16);
            z0 += __shfl_xor(z0, 32); z1 += __shfl_xor(z1, 32);

            if (kg == 0) {
                v_out[gout] = net ? v1A[s] : vxA[s];
                const float zz0 = z0 + llr_b[0], zz1 = z1 + llr_b[1];
                const float m   = fmaxf(zz0, zz1);
                const float ex0 = expf(zz0 - m), ex1 = expf(zz1 - m);
                const float inv = 1.0f / (ex0 + ex1);
                const float p0s = ex0 * inv, p1s = ex1 * inv;
                const float c0  = fminf(fmaxf(p0s, EPS_), 1.0f - EPS_);
                const float c1  = fminf(fmaxf(p1s, EPS_), 1.0f - EPS_);
                const int   lab = net ? (v1A[s] & 1) : vxA[s];
                const float loss = -logf(lab ? c1 : c0);
                loss_out[(b * T_ + t + 1) * N_ + io2] = loss;
                pscr[(size_t)(b * T_ + t + 1) * N_ + io2] = make_float2(p0s, p1s);
            }
        }
    }
}

// ---------------------------------------------------------------------------
// Fused tail (t = 5..11): r14/r16-proven version + folded pred transpose.
// ---------------------------------------------------------------------------
__global__ __launch_bounds__(256, 2) void fused_tail(
    const short* __restrict__ e_hi, const short* __restrict__ e_lo,
    const int* __restrict__ v_in,
    const short* __restrict__ wblob,
    const float* __restrict__ cn_b1, const float* __restrict__ cn_b2,
    const float* __restrict__ bn_b2, const float* __restrict__ contrib,
    const float* __restrict__ llr_w, const float* __restrict__ llr_b,
    float* __restrict__ loss_out, float2* __restrict__ pscr,
    float* __restrict__ pred1, float* __restrict__ pred2)
{
    __shared__ __align__(16) short w2lds[16384];       // 32 KB
    __shared__ __align__(16) short ehl[2][128 * ESTR]; // 2 x 18KB hi/lo planes
    __shared__ int v_lds[128];
    __shared__ __align__(16) float cst[448];           // contrib|b1|b2c|b2b|llr
    const int tid = threadIdx.x;
    {
        uint4* dst = (uint4*)w2lds;
        const uint4* src = (const uint4*)(wblob + OFF_C2TH);
#pragma unroll
        for (int i = 0; i < 8; ++i)
            dst[tid + i * 256] = src[tid + i * 256];
    }
    if (tid < 128) { cst[tid] = contrib[tid]; cst[320 + tid] = llr_w[tid]; }
    if (tid < 64) {
        cst[128 + tid] = cn_b1[tid];
        cst[192 + tid] = cn_b2[tid];
        cst[256 + tid] = bn_b2[tid];
    }
    const int b = blockIdx.x >> 5, ch = blockIdx.x & 31;
    const int base_row = b * N_ + ch * 128;
    {
        const int r = tid >> 1, seg = tid & 1;
        const size_t g = (size_t)(base_row + r) * D_ + seg * 32;
#pragma unroll
        for (int pl = 0; pl < 2; ++pl) {
            const short* sp = (pl ? e_lo : e_hi) + g;
            short* dp = &ehl[pl][r * ESTR + seg * 32];
            *(uint4*)dp        = *(const uint4*)sp;
            *(uint4*)(dp + 8)  = *(const uint4*)(sp + 8);
            *(uint4*)(dp + 16) = *(const uint4*)(sp + 16);
            *(uint4*)(dp + 24) = *(const uint4*)(sp + 24);
        }
        if (tid < 128) v_lds[tid] = v_in[base_row + tid];
    }

    const int lane = tid & 63;
    const int pr = lane & 15, kg = lane >> 4;
    const int wid = tid >> 6;
    const int net = wid >> 1, sg = wid & 1;
    const int w2b = net * 8192;

    short8 w1h[16], w1l[16];
    {
        const short* wh = wblob + (net ? OFF_B1H : OFF_C1H);
        const short* wl = wblob + (net ? OFF_B1L : OFF_C1L);
#pragma unroll
        for (int f = 0; f < 16; ++f) {
            const int fo = (f * 64 + lane) * 8;
            w1h[f] = *(const short8*)(wh + fo);
            w1l[f] = *(const short8*)(wl + fo);
        }
    }
    const float* b2c = net ? (cst + 256) : (cst + 192);
    __syncthreads();

    int Lh = 64;
#pragma unroll 1
    for (int t = 5; t < 12; ++t, Lh >>= 1) {
        int pA[2], v1A[2], vxA[2];
        f32x4 acc[2][4];
#pragma unroll
        for (int s = 0; s < 2; ++s) {
            const int p = sg * 32 + s * 16 + pr;
            pA[s] = p;
            const int v0 = v_lds[2 * p], v1 = v_lds[2 * p + 1];
            v1A[s] = v1; vxA[s] = (v0 ^ v1) & 1;
#pragma unroll
            for (int mt = 0; mt < 4; ++mt) {
                if (net) {
                    const f4 cb = LD4(cst + vxA[s] * 64 + mt * 16 + kg * 4);
                    acc[s][mt] = (f32x4){cb.x, cb.y, cb.z, cb.w};
                } else {
                    const f4 bc = LD4(cst + 128 + mt * 16 + kg * 4);
                    acc[s][mt] = (f32x4){bc.x, bc.y, bc.z, bc.w};
                }
            }
        }

#pragma unroll
        for (int kt = 0; kt < 4; ++kt) {
            short8 Eh[2], El[2];
#pragma unroll
            for (int s = 0; s < 2; ++s) {
                const int off = (2 * pA[s] + (kt >> 1)) * ESTR + (kt & 1) * 32 + kg * 8;
                Eh[s] = *(const short8*)&ehl[0][off];
                El[s] = *(const short8*)&ehl[1][off];
            }
#pragma unroll
            for (int mt = 0; mt < 4; ++mt) {
                const short8 wh = w1h[kt * 4 + mt], wl = w1l[kt * 4 + mt];
#pragma unroll
                for (int s = 0; s < 2; ++s) {
                    acc[s][mt] = MFMA(wh, Eh[s], acc[s][mt]);
                    acc[s][mt] = MFMA(wl, Eh[s], acc[s][mt]);
                    acc[s][mt] = MFMA(wh, El[s], acc[s][mt]);
                }
            }
        }

        s4b hh[2][4], hl[2][4];
#pragma unroll
        for (int s = 0; s < 2; ++s)
#pragma unroll
            for (int ks = 0; ks < 4; ++ks)
#pragma unroll
                for (int e2 = 0; e2 < 4; ++e2) {
                    short sh, sl2;
                    splitbf(fmaxf(acc[s][ks][e2], 0.f), sh, sl2);
                    hh[s][ks][e2] = sh; hl[s][ks][e2] = sl2;
                }

        f32x4 o[2][4];
#pragma unroll
        for (int mt2 = 0; mt2 < 4; ++mt2) {
            const f4 bb = LD4(b2c + mt2 * 16 + kg * 4);
#pragma unroll
            for (int s = 0; s < 2; ++s) o[s][mt2] = (f32x4){bb.x, bb.y, bb.z, bb.w};
        }
#pragma unroll
        for (int ks = 0; ks < 4; ++ks)
#pragma unroll
            for (int mt2 = 0; mt2 < 4; ++mt2) {
                const int fo4 = ((ks * 4 + mt2) * 64 + lane) * 4;
                const s4b wh = *(const s4b*)(w2lds + w2b + fo4);
                const s4b wl = *(const s4b*)(w2lds + w2b + 4096 + fo4);
#pragma unroll
                for (int s = 0; s < 2; ++s) {
                    o[s][mt2] = MFMA16(wh, hh[s][ks], o[s][mt2]);
                    o[s][mt2] = MFMA16(wl, hh[s][ks], o[s][mt2]);
                    o[s][mt2] = MFMA16(wh, hl[s][ks], o[s][mt2]);
                }
            }

        int iolA[2], vnA[2];
        uint4 pkh[2][2], pkl[2][2];
#pragma unroll
        for (int s = 0; s < 2; ++s) {
            const int p = pA[s];
            const int j = p & (Lh - 1);
            const int iol = 2 * p - j + (net ? Lh : 0);
            iolA[s] = iol;
            vnA[s]  = net ? v1A[s] : vxA[s];

            float z0 = 0.f, z1 = 0.f;
            union { short sv[16]; uint4 v[2]; } ph, pl;
#pragma unroll
            for (int mt2 = 0; mt2 < 4; ++mt2) {
#pragma unroll
                for (int e2 = 0; e2 < 4; ++e2) {
                    short sh, sl2;
                    splitbf(o[s][mt2][e2], sh, sl2);
                    ph.sv[mt2 * 4 + e2] = sh; pl.sv[mt2 * 4 + e2] = sl2;
                }
                const int f0 = mt2 * 16 + kg * 4;
                const f4 wA = LD4(cst + 320 + 2 * f0);
                const f4 wB = LD4(cst + 320 + 2 * f0 + 4);
                z0 += o[s][mt2][0] * wA.x + o[s][mt2][1] * wA.z +
                      o[s][mt2][2] * wB.x + o[s][mt2][3] * wB.z;
                z1 += o[s][mt2][0] * wA.y + o[s][mt2][1] * wA.w +
                      o[s][mt2][2] * wB.y + o[s][mt2][3] * wB.w;
            }
            pkh[s][0] = ph.v[0]; pkh[s][1] = ph.v[1];
            pkl[s][0] = pl.v[0]; pkl[s][1] = pl.v[1];
            z0 += __shfl_xor(z0, 16); z1 += __shfl_xor(z1, 16);
            z0 += __shfl_xor(z0, 32); z1 += __shfl_xor(z1, 32);

            if (kg == 0) {
                const int io = ch * 128 + iol;
                const float zz0 = z0 + llr_b[0], zz1 = z1 + llr_b[1];
                const float m   = fmaxf(zz0, zz1);
                const float ex0 = expf(zz0 - m), ex1 = expf(zz1 - m);
                const float inv = 1.0f / (ex0 + ex1);
                const float p0s = ex0 * inv, p1s = ex1 * inv;
                const float c0  = fminf(fmaxf(p0s, EPS_), 1.0f - EPS_);
                const float c1  = fminf(fmaxf(p1s, EPS_), 1.0f - EPS_);
                const int   lab = net ? (v1A[s] & 1) : vxA[s];
                const float loss = -logf(lab ? c1 : c0);
                loss_out[(b * T_ + t) * N_ + io] = loss;
                pscr[(size_t)(b * T_ + t) * N_ + io] = make_float2(p0s, p1s);
            }
        }
        __syncthreads();   // all e/v reads of this stage complete

#pragma unroll
        for (int s = 0; s < 2; ++s) {
            short* dh = &ehl[0][iolA[s] * ESTR + kg * 16];
            short* dl = &ehl[1][iolA[s] * ESTR + kg * 16];
            *(uint4*)dh       = pkh[s][0];
            *(uint4*)(dh + 8) = pkh[s][1];
            *(uint4*)dl       = pkl[s][0];
            *(uint4*)(dl + 8) = pkl[s][1];
            if (kg == 0) v_lds[iolA[s]] = vnA[s];
        }
        __syncthreads();   // writes visible for next stage
    }

    // ---- folded pred transpose: this block's 128 positions ----
    if (tid < 128) {
        const int io  = ch * 128 + tid;
        const int idx = b * N_ + io;
        float2 v[T_];
#pragma unroll
        for (int t = 0; t < T_; ++t)
            v[t] = pscr[(size_t)(b * T_ + t) * N_ + io];
        float* d1 = pred1 + (size_t)idx * (T_ * 2);
        float* d2 = pred2 + (size_t)idx * (T_ * 2);
#pragma unroll
        for (int q = 0; q < 6; ++q) {
            const f4 w = make_float4(v[2 * q].x, v[2 * q].y, v[2 * q + 1].x, v[2 * q + 1].y);
            *(f4*)(d1 + 4 * q) = w;
            *(f4*)(d2 + 4 * q) = w;
        }
    }
}

// ---------------------------------------------------------------------------
extern "C" void kernel_launch(void* const* d_in, const int* in_sizes, int n_in,
                              void* d_out, int out_size, void* d_ws, size_t ws_size,
                              hipStream_t stream)
{
    const int*   x      = (const int*)  d_in[0];
    const float* y      = (const float*)d_in[1];
    const float* emb_w1 = (const float*)d_in[2];
    const float* emb_b1 = (const float*)d_in[3];
    const float* emb_w2 = (const float*)d_in[4];
    const float* emb_b2 = (const float*)d_in[5];
    const float* cn_w1  = (const float*)d_in[6];
    const float* cn_b1  = (const float*)d_in[7];
    const float* cn_w2  = (const float*)d_in[8];
    const float* cn_b2  = (const float*)d_in[9];
    const float* bn_w1  = (const float*)d_in[10];
    const float* bn_b1  = (const float*)d_in[11];
    const float* bn_w2  = (const float*)d_in[12];
    const float* bn_b2  = (const float*)d_in[13];
    const float* llr_w  = (const float*)d_in[14];
    const float* llr_b  = (const float*)d_in[15];
    const float* label_emb = (const float*)d_in[16];

    float* out      = (float*)d_out;
    float* loss_out = out;
    float* pred1    = out + (size_t)B_ * T_ * N_;
    float* pred2    = pred1 + (size_t)B_ * N_ * T_ * 2;

    const size_t EPLANE = (size_t)B_ * N_ * D_;
    short* eh_a = (short*)d_ws;
    short* el_a = eh_a + EPLANE;
    short* eh_b = el_a + EPLANE;
    short* el_b = eh_b + EPLANE;
    int*   v_a  = (int*)(el_b + EPLANE);
    int*   v_b  = v_a + B_ * N_;
    float2* pscr = (float2*)(v_b + B_ * N_);
    short* wblob = (short*)(pscr + (size_t)B_ * T_ * N_);
    float* contrib = (float*)(wblob + WBLOB_SHORTS);

    prep_kernel<<<dim3(49), dim3(256), 0, stream>>>(
        cn_w1, cn_w2, bn_w1, bn_w2, bn_b1, label_emb, wblob, contrib);

    emb_kernel<<<dim3(B_ * N_ / 128), dim3(256), 0, stream>>>(
        x, y, emb_w1, emb_b1, emb_w2, emb_b2, eh_a, el_a, v_a);

    // stages 0+1 fused (e_a -> e_b)
    fused_early<<<dim3(B_ * N_ / 2 / 64), dim3(256), 0, stream>>>(
        eh_a, el_a, v_a, eh_b, el_b, v_b, wblob,
        cn_b1, cn_b2, bn_b2, contrib, llr_w, llr_b,
        loss_out, pscr, 0, 11);

    // stages 2+3 fused (e_b -> e_a)
    fused_early<<<dim3(B_ * N_ / 2 / 64), dim3(256), 0, stream>>>(
        eh_b, el_b, v_b, eh_a, el_a, v_a, wblob,
        cn_b1, cn_b2, bn_b2, contrib, llr_w, llr_b,
        loss_out, pscr, 2, 9);

    // stage 4 (e_a -> e_b)
    stage_kernel<<<dim3(B_ * N_ / 2 / 256), dim3(512), 0, stream>>>(
        eh_a, el_a, v_a, eh_b, el_b, v_b, wblob,
        cn_b1, cn_b2, bn_b2, contrib, llr_w, llr_b,
        loss_out, pscr, 4, 7);

    // stages 5..11 fused in LDS (e_b) + pred transpose
    fused_tail<<<dim3(1024), dim3(256), 0, stream>>>(
        eh_b, el_b, v_b, wblob,
        cn_b1, cn_b2, bn_b2, contrib, llr_w, llr_b,
        loss_out, pscr, pred1, pred2);
}

// Round 18
// 147.811 us; speedup vs baseline: 2.0066x; 1.2807x over previous
//
#include <hip/hip_runtime.h>
#include <math.h>

#define B_ 32
#define N_ 4096
#define D_ 64
#define T_ 12
#define EPS_ 1e-7f
#define ESTR 72   // e-plane LDS row stride in SHORTS (144B, 16B-aligned)

typedef float4 f4;
#define LD4(p) (*(const float4*)(p))

typedef __attribute__((ext_vector_type(8))) short short8;
typedef __attribute__((ext_vector_type(4))) short s4b;
typedef __attribute__((ext_vector_type(4))) float f32x4;
#define MFMA(a, b, c)   __builtin_amdgcn_mfma_f32_16x16x32_bf16(a, b, c, 0, 0, 0)
#define MFMA16(a, b, c) __builtin_amdgcn_mfma_f32_16x16x16bf16_1k(a, b, c, 0, 0, 0)

// weight blob offsets (shorts) in global wblob
#define OFF_C1H 0
#define OFF_C1L 8192
#define OFF_B1H 16384
#define OFF_B1L 24576
#define OFF_C2TH 32768
#define OFF_C2TL 36864
#define OFF_B2TH 40960
#define OFF_B2TL 45056
#define OFF_E2TH 49152
#define OFF_E2TL 53248
#define WBLOB_SHORTS 57344

__device__ __forceinline__ void splitbf(float a, short& h, short& l) {
    unsigned x = __float_as_uint(a);
    h = (short)(x >> 16);
    float r = a - __uint_as_float(x & 0xffff0000u);
    l = (short)(__float_as_uint(r) >> 16);
}

// sigma: involutive feature permutation for e-storage (swap bits[5:4]<->[3:2])
__device__ __forceinline__ int sigma_(int f) {
    return (((f >> 2) & 3) << 4) | (((f >> 4) & 3) << 2) | (f & 3);
}

// ---------------------------------------------------------------------------
// Prep (parallel): 0-31 w1 packs, 32-47 w2^T packs, 48-63 emb w2^T, 64 contrib.
// ---------------------------------------------------------------------------
__global__ void prep_kernel(
    const float* __restrict__ cn_w1, const float* __restrict__ cn_w2,
    const float* __restrict__ bn_w1, const float* __restrict__ bn_w2,
    const float* __restrict__ bn_b1, const float* __restrict__ label_emb,
    const float* __restrict__ emb_w2,
    short* __restrict__ wblob, float* __restrict__ contrib)
{
    const int bid = blockIdx.x, tid = threadIdx.x;
    if (bid < 32) {                                  // w1 packs (K=128)
        const int idx = bid * 256 + tid;
        const int e = idx & 7, l = (idx >> 3) & 63, fb = idx >> 9;
        const int kt = fb >> 2, mt = fb & 3;
        const int f_lin = (kt & 1) * 32 + (l >> 4) * 8 + e;
        const int k = (kt >> 1) * 64 + sigma_(f_lin);
        const int n = mt * 16 + (l & 15);
        short h, lo;
        splitbf(cn_w1[k * 64 + n], h, lo);
        wblob[OFF_C1H + idx] = h; wblob[OFF_C1L + idx] = lo;
        splitbf(bn_w1[k * 64 + n], h, lo);
        wblob[OFF_B1H + idx] = h; wblob[OFF_B1L + idx] = lo;
    } else if (bid < 48) {                           // w2^T packs (16x16x16 A)
        const int idx = (bid - 32) * 256 + tid;
        const int e = idx & 3, l = (idx >> 2) & 63, fb = idx >> 8;
        const int ks = fb >> 2, mt2 = fb & 3;
        const int k = ks * 16 + (l >> 4) * 4 + e;
        const int n = mt2 * 16 + (l & 15);
        short h, lo;
        splitbf(cn_w2[k * 64 + n], h, lo);
        wblob[OFF_C2TH + idx] = h; wblob[OFF_C2TL + idx] = lo;
        splitbf(bn_w2[k * 64 + n], h, lo);
        wblob[OFF_B2TH + idx] = h; wblob[OFF_B2TL + idx] = lo;
    } else if (bid < 64) {                           // emb w2^T packs
        const int idx = (bid - 48) * 256 + tid;
        const int e = idx & 3, l = (idx >> 2) & 63, fb = idx >> 8;
        const int ks = fb >> 2, mt2 = fb & 3;
        const int k = ks * 16 + (l >> 4) * 4 + e;
        const int n = mt2 * 16 + (l & 15);
        short h, lo;
        splitbf(emb_w2[k * 64 + n], h, lo);
        wblob[OFF_E2TH + idx] = h; wblob[OFF_E2TL + idx] = lo;
    } else if (tid < 128) {                          // contrib
        const int c = tid >> 6, n = tid & 63;
        float s = bn_b1[n];
#pragma unroll 8
        for (int kk = 0; kk < 64; ++kk)
            s = fmaf(label_emb[c * 64 + kk], bn_w1[(128 + kk) * 64 + n], s);
        contrib[c * 64 + n] = s;
    }
}

// ---------------------------------------------------------------------------
// Fused HEAD: emb + stages t=0..4, all intermediates in LDS (run-major rows:
// pair d -> rows 2d,2d+1 at every stage). 1024 blocks x 256 thr (4 waves:
// net = wid>>1, sg = wid&1). Writes stage-4 e/v to global. W1 in regs.
// ---------------------------------------------------------------------------
__global__ __launch_bounds__(256, 2) void fused_head(
    const int* __restrict__ x, const float* __restrict__ y,
    const float* __restrict__ emb_w1, const float* __restrict__ emb_b1,
    const float* __restrict__ emb_b2,
    short* __restrict__ eo_hi, short* __restrict__ eo_lo, int* __restrict__ v_out,
    const short* __restrict__ wblob,
    const float* __restrict__ cn_b1, const float* __restrict__ cn_b2,
    const float* __restrict__ bn_b2, const float* __restrict__ contrib,
    const float* __restrict__ llr_w, const float* __restrict__ llr_b,
    float* __restrict__ loss_out, float2* __restrict__ pscr)
{
    __shared__ __align__(16) short w2lds[16384];       // 32 KB (cn|bn w2t)
    __shared__ __align__(16) short ehl[2][128 * ESTR]; // e hi/lo planes
    __shared__ int v_lds[128];
    __shared__ __align__(16) float cst[704];
    const int tid = threadIdx.x;
    {
        uint4* dst = (uint4*)w2lds;
        const uint4* src = (const uint4*)(wblob + OFF_C2TH);
#pragma unroll
        for (int i = 0; i < 8; ++i)
            dst[tid + i * 256] = src[tid + i * 256];
    }
    if (tid < 128) {
        cst[tid] = contrib[tid];
        cst[320 + tid] = llr_w[tid];
        cst[448 + tid] = emb_w1[tid];
    }
    if (tid < 64) {
        cst[128 + tid] = cn_b1[tid];
        cst[192 + tid] = cn_b2[tid];
        cst[256 + tid] = bn_b2[tid];
        cst[576 + tid] = emb_b1[tid];
        cst[640 + tid] = emb_b2[tid];
    }

    const int lane = tid & 63;
    const int pr = lane & 15, kg = lane >> 4;
    const int wid = tid >> 6;
    const int net = wid >> 1, sg = wid & 1;
    const int w2b = net * 8192;
    const int gpos0 = blockIdx.x * 128;        // flat position base
    const int b     = gpos0 >> 12;
    const int posb  = gpos0 & (N_ - 1);        // in-batch position base

    short8 w1h[16], w1l[16];
    {
        const short* wh = wblob + (net ? OFF_B1H : OFF_C1H);
        const short* wl = wblob + (net ? OFF_B1L : OFF_C1L);
#pragma unroll
        for (int f = 0; f < 16; ++f) {
            const int fo = (f * 64 + lane) * 8;
            w1h[f] = *(const short8*)(wh + fo);
            w1l[f] = *(const short8*)(wl + fo);
        }
    }
    const float* b2c = net ? (cst + 256) : (cst + 192);
    __syncthreads();   // cst/w2lds ready

    // ======== emb phase: 2 positions per thread, e -> LDS rows ========
    {
        s4b we2h[16], we2l[16];
#pragma unroll
        for (int f = 0; f < 16; ++f) {
            const int fo4 = (f * 64 + lane) * 4;
            we2h[f] = *(const s4b*)(wblob + OFF_E2TH + fo4);
            we2l[f] = *(const s4b*)(wblob + OFF_E2TL + fo4);
        }
#pragma unroll
        for (int sub = 0; sub < 2; ++sub) {
            const int pos = wid * 32 + sub * 16 + pr;
            const float2 yv = *(const float2*)(y + 2 * (gpos0 + pos));
            s4b hh[4], hl[4];
#pragma unroll
            for (int ks = 0; ks < 4; ++ks)
#pragma unroll
                for (int e2 = 0; e2 < 4; ++e2) {
                    const int f = ks * 16 + kg * 4 + e2;
                    const float hv = fmaxf(
                        fmaf(yv.y, cst[512 + f], fmaf(yv.x, cst[448 + f], cst[576 + f])), 0.f);
                    short sh, sl2; splitbf(hv, sh, sl2);
                    hh[ks][e2] = sh; hl[ks][e2] = sl2;
                }
            f32x4 o[4];
#pragma unroll
            for (int mt2 = 0; mt2 < 4; ++mt2) {
                const f4 bb = LD4(cst + 640 + mt2 * 16 + kg * 4);
                o[mt2] = (f32x4){bb.x, bb.y, bb.z, bb.w};
            }
#pragma unroll
            for (int ks = 0; ks < 4; ++ks)
#pragma unroll
                for (int mt2 = 0; mt2 < 4; ++mt2) {
                    o[mt2] = MFMA16(we2h[ks * 4 + mt2], hh[ks], o[mt2]);
                    o[mt2] = MFMA16(we2l[ks * 4 + mt2], hh[ks], o[mt2]);
                    o[mt2] = MFMA16(we2h[ks * 4 + mt2], hl[ks], o[mt2]);
                }
            union { short sv[16]; uint4 v[2]; } ph, pl;
#pragma unroll
            for (int mt2 = 0; mt2 < 4; ++mt2)
#pragma unroll
                for (int e2 = 0; e2 < 4; ++e2) {
                    short sh, sl2;
                    splitbf(o[mt2][e2], sh, sl2);
                    ph.sv[mt2 * 4 + e2] = sh; pl.sv[mt2 * 4 + e2] = sl2;
                }
            short* dh = &ehl[0][pos * ESTR + kg * 16];
            short* dl = &ehl[1][pos * ESTR + kg * 16];
            *(uint4*)dh       = ph.v[0];
            *(uint4*)(dh + 8) = ph.v[1];
            *(uint4*)dl       = pl.v[0];
            *(uint4*)(dl + 8) = pl.v[1];
            if (kg == 0) v_lds[pos] = x[gpos0 + pos];
        }
    }
    __syncthreads();

    // ======== stages s = 0..4 ========
#pragma unroll 1
    for (int s = 0; s < 5; ++s) {
        const int prl    = 6 - s;            // log2(pairs per run)
        const int Lhs    = 2048 >> s;
        const int rowlen = 128 >> s;

        int qA[2], CnA[2], orowA[2], v1A[2], vxA[2];
        f32x4 acc[2][4];
#pragma unroll
        for (int st = 0; st < 2; ++st) {
            const int d = sg * 32 + st * 16 + pr;
            const int r = d >> prl;
            const int q = d & ((1 << prl) - 1);
            int G = posb;
            for (int i = 0; i < s; ++i) {
                const int Lhi = 2048 >> i;
                G = G - ((G >> 1) & (Lhi - 1)) + (((r >> (s - 1 - i)) & 1) ? Lhi : 0);
            }
            qA[st]  = q;
            CnA[st] = G - ((G >> 1) & (Lhs - 1));
            orowA[st] = r * rowlen + net * (rowlen >> 1) + q;
            const int v0 = v_lds[2 * d], v1 = v_lds[2 * d + 1];
            v1A[st] = v1; vxA[st] = (v0 ^ v1) & 1;
#pragma unroll
            for (int mt = 0; mt < 4; ++mt) {
                if (net) {
                    const f4 cb = LD4(cst + vxA[st] * 64 + mt * 16 + kg * 4);
                    acc[st][mt] = (f32x4){cb.x, cb.y, cb.z, cb.w};
                } else {
                    const f4 bc = LD4(cst + 128 + mt * 16 + kg * 4);
                    acc[st][mt] = (f32x4){bc.x, bc.y, bc.z, bc.w};
                }
            }
        }

#pragma unroll
        for (int kt = 0; kt < 4; ++kt) {
            short8 Eh[2], El[2];
#pragma unroll
            for (int st = 0; st < 2; ++st) {
                const int d = sg * 32 + st * 16 + pr;
                const int off = (2 * d + (kt >> 1)) * ESTR + (kt & 1) * 32 + kg * 8;
                Eh[st] = *(const short8*)&ehl[0][off];
                El[st] = *(const short8*)&ehl[1][off];
            }
#pragma unroll
            for (int mt = 0; mt < 4; ++mt) {
                const short8 wh = w1h[kt * 4 + mt], wl = w1l[kt * 4 + mt];
#pragma unroll
                for (int st = 0; st < 2; ++st) {
                    acc[st][mt] = MFMA(wh, Eh[st], acc[st][mt]);
                    acc[st][mt] = MFMA(wl, Eh[st], acc[st][mt]);
                    acc[st][mt] = MFMA(wh, El[st], acc[st][mt]);
                }
            }
        }

        s4b hh[2][4], hl[2][4];
#pragma unroll
        for (int st = 0; st < 2; ++st)
#pragma unroll
            for (int ks = 0; ks < 4; ++ks)
#pragma unroll
                for (int e2 = 0; e2 < 4; ++e2) {
                    short sh, sl2;
                    splitbf(fmaxf(acc[st][ks][e2], 0.f), sh, sl2);
                    hh[st][ks][e2] = sh; hl[st][ks][e2] = sl2;
                }

        f32x4 o[2][4];
#pragma unroll
        for (int mt2 = 0; mt2 < 4; ++mt2) {
            const f4 bb = LD4(b2c + mt2 * 16 + kg * 4);
#pragma unroll
            for (int st = 0; st < 2; ++st) o[st][mt2] = (f32x4){bb.x, bb.y, bb.z, bb.w};
        }
#pragma unroll
        for (int ks = 0; ks < 4; ++ks)
#pragma unroll
            for (int mt2 = 0; mt2 < 4; ++mt2) {
                const int fo4 = ((ks * 4 + mt2) * 64 + lane) * 4;
                const s4b wh = *(const s4b*)(w2lds + w2b + fo4);
                const s4b wl = *(const s4b*)(w2lds + w2b + 4096 + fo4);
#pragma unroll
                for (int st = 0; st < 2; ++st) {
                    o[st][mt2] = MFMA16(wh, hh[st][ks], o[st][mt2]);
                    o[st][mt2] = MFMA16(wl, hh[st][ks], o[st][mt2]);
                    o[st][mt2] = MFMA16(wh, hl[st][ks], o[st][mt2]);
                }
            }

        uint4 pkh[2][2], pkl[2][2];
        int vnA[2];
#pragma unroll
        for (int st = 0; st < 2; ++st) {
            const int io = CnA[st] + qA[st] + net * Lhs;
            vnA[st] = net ? v1A[st] : vxA[st];

            float z0 = 0.f, z1 = 0.f;
            union { short sv[16]; uint4 v[2]; } ph, pl;
#pragma unroll
            for (int mt2 = 0; mt2 < 4; ++mt2) {
#pragma unroll
                for (int e2 = 0; e2 < 4; ++e2) {
                    short sh, sl2;
                    splitbf(o[st][mt2][e2], sh, sl2);
                    ph.sv[mt2 * 4 + e2] = sh; pl.sv[mt2 * 4 + e2] = sl2;
                }
                const int f0 = mt2 * 16 + kg * 4;
                const f4 wA = LD4(cst + 320 + 2 * f0);
                const f4 wB = LD4(cst + 320 + 2 * f0 + 4);
                z0 += o[st][mt2][0] * wA.x + o[st][mt2][1] * wA.z +
                      o[st][mt2][2] * wB.x + o[st][mt2][3] * wB.z;
                z1 += o[st][mt2][0] * wA.y + o[st][mt2][1] * wA.w +
                      o[st][mt2][2] * wB.y + o[st][mt2][3] * wB.w;
            }
            pkh[st][0] = ph.v[0]; pkh[st][1] = ph.v[1];
            pkl[st][0] = pl.v[0]; pkl[st][1] = pl.v[1];
            z0 += __shfl_xor(z0, 16); z1 += __shfl_xor(z1, 16);
            z0 += __shfl_xor(z0, 32); z1 += __shfl_xor(z1, 32);

            if (kg == 0) {
                const float zz0 = z0 + llr_b[0], zz1 = z1 + llr_b[1];
                const float m   = fmaxf(zz0, zz1);
                const float ex0 = expf(zz0 - m), ex1 = expf(zz1 - m);
                const float inv = 1.0f / (ex0 + ex1);
                const float p0s = ex0 * inv, p1s = ex1 * inv;
                const float c0  = fminf(fmaxf(p0s, EPS_), 1.0f - EPS_);
                const float c1  = fminf(fmaxf(p1s, EPS_), 1.0f - EPS_);
                const int   lab = net ? (v1A[st] & 1) : vxA[st];
                const float loss = -logf(lab ? c1 : c0);
                loss_out[(b * T_ + s) * N_ + io] = loss;
                pscr[(size_t)(b * T_ + s) * N_ + io] = make_float2(p0s, p1s);
            }

            if (s == 4) {   // final: write e/v to global
                const size_t eb = (size_t)(b * N_ + io) * D_ + kg * 16;
                *(uint4*)(eo_hi + eb)     = ph.v[0];
                *(uint4*)(eo_hi + eb + 8) = ph.v[1];
                *(uint4*)(eo_lo + eb)     = pl.v[0];
                *(uint4*)(eo_lo + eb + 8) = pl.v[1];
                if (kg == 0) v_out[b * N_ + io] = vnA[st];
            }
        }

        if (s < 4) {
            __syncthreads();   // all e/v reads of this stage complete
#pragma unroll
            for (int st = 0; st < 2; ++st) {
                short* dh = &ehl[0][orowA[st] * ESTR + kg * 16];
                short* dl = &ehl[1][orowA[st] * ESTR + kg * 16];
                *(uint4*)dh       = pkh[st][0];
                *(uint4*)(dh + 8) = pkh[st][1];
                *(uint4*)dl       = pkl[st][0];
                *(uint4*)(dl + 8) = pkl[st][1];
                if (kg == 0) v_lds[orowA[st]] = vnA[st];
            }
            __syncthreads();   // writes visible for next stage
        }
    }
}

// ---------------------------------------------------------------------------
// Fused tail (t = 5..11): r14/r16-proven version + folded pred transpose.
// ---------------------------------------------------------------------------
__global__ __launch_bounds__(256, 2) void fused_tail(
    const short* __restrict__ e_hi, const short* __restrict__ e_lo,
    const int* __restrict__ v_in,
    const short* __restrict__ wblob,
    const float* __restrict__ cn_b1, const float* __restrict__ cn_b2,
    const float* __restrict__ bn_b2, const float* __restrict__ contrib,
    const float* __restrict__ llr_w, const float* __restrict__ llr_b,
    float* __restrict__ loss_out, float2* __restrict__ pscr,
    float* __restrict__ pred1, float* __restrict__ pred2)
{
    __shared__ __align__(16) short w2lds[16384];       // 32 KB
    __shared__ __align__(16) short ehl[2][128 * ESTR]; // 2 x 18KB hi/lo planes
    __shared__ int v_lds[128];
    __shared__ __align__(16) float cst[448];
    const int tid = threadIdx.x;
    {
        uint4* dst = (uint4*)w2lds;
        const uint4* src = (const uint4*)(wblob + OFF_C2TH);
#pragma unroll
        for (int i = 0; i < 8; ++i)
            dst[tid + i * 256] = src[tid + i * 256];
    }
    if (tid < 128) { cst[tid] = contrib[tid]; cst[320 + tid] = llr_w[tid]; }
    if (tid < 64) {
        cst[128 + tid] = cn_b1[tid];
        cst[192 + tid] = cn_b2[tid];
        cst[256 + tid] = bn_b2[tid];
    }
    const int b = blockIdx.x >> 5, ch = blockIdx.x & 31;
    const int base_row = b * N_ + ch * 128;
    {
        const int r = tid >> 1, seg = tid & 1;
        const size_t g = (size_t)(base_row + r) * D_ + seg * 32;
#pragma unroll
        for (int pl = 0; pl < 2; ++pl) {
            const short* sp = (pl ? e_lo : e_hi) + g;
            short* dp = &ehl[pl][r * ESTR + seg * 32];
            *(uint4*)dp        = *(const uint4*)sp;
            *(uint4*)(dp + 8)  = *(const uint4*)(sp + 8);
            *(uint4*)(dp + 16) = *(const uint4*)(sp + 16);
            *(uint4*)(dp + 24) = *(const uint4*)(sp + 24);
        }
        if (tid < 128) v_lds[tid] = v_in[base_row + tid];
    }

    const int lane = tid & 63;
    const int pr = lane & 15, kg = lane >> 4;
    const int wid = tid >> 6;
    const int net = wid >> 1, sg = wid & 1;
    const int w2b = net * 8192;

    short8 w1h[16], w1l[16];
    {
        const short* wh = wblob + (net ? OFF_B1H : OFF_C1H);
        const short* wl = wblob + (net ? OFF_B1L : OFF_C1L);
#pragma unroll
        for (int f = 0; f < 16; ++f) {
            const int fo = (f * 64 + lane) * 8;
            w1h[f] = *(const short8*)(wh + fo);
            w1l[f] = *(const short8*)(wl + fo);
        }
    }
    const float* b2c = net ? (cst + 256) : (cst + 192);
    __syncthreads();

    int Lh = 64;
#pragma unroll 1
    for (int t = 5; t < 12; ++t, Lh >>= 1) {
        int pA[2], v1A[2], vxA[2];
        f32x4 acc[2][4];
#pragma unroll
        for (int s = 0; s < 2; ++s) {
            const int p = sg * 32 + s * 16 + pr;
            pA[s] = p;
            const int v0 = v_lds[2 * p], v1 = v_lds[2 * p + 1];
            v1A[s] = v1; vxA[s] = (v0 ^ v1) & 1;
#pragma unroll
            for (int mt = 0; mt < 4; ++mt) {
                if (net) {
                    const f4 cb = LD4(cst + vxA[s] * 64 + mt * 16 + kg * 4);
                    acc[s][mt] = (f32x4){cb.x, cb.y, cb.z, cb.w};
                } else {
                    const f4 bc = LD4(cst + 128 + mt * 16 + kg * 4);
                    acc[s][mt] = (f32x4){bc.x, bc.y, bc.z, bc.w};
                }
            }
        }

#pragma unroll
        for (int kt = 0; kt < 4; ++kt) {
            short8 Eh[2], El[2];
#pragma unroll
            for (int s = 0; s < 2; ++s) {
                const int off = (2 * pA[s] + (kt >> 1)) * ESTR + (kt & 1) * 32 + kg * 8;
                Eh[s] = *(const short8*)&ehl[0][off];
                El[s] = *(const short8*)&ehl[1][off];
            }
#pragma unroll
            for (int mt = 0; mt < 4; ++mt) {
                const short8 wh = w1h[kt * 4 + mt], wl = w1l[kt * 4 + mt];
#pragma unroll
                for (int s = 0; s < 2; ++s) {
                    acc[s][mt] = MFMA(wh, Eh[s], acc[s][mt]);
                    acc[s][mt] = MFMA(wl, Eh[s], acc[s][mt]);
                    acc[s][mt] = MFMA(wh, El[s], acc[s][mt]);
                }
            }
        }

        s4b hh[2][4], hl[2][4];
#pragma unroll
        for (int s = 0; s < 2; ++s)
#pragma unroll
            for (int ks = 0; ks < 4; ++ks)
#pragma unroll
                for (int e2 = 0; e2 < 4; ++e2) {
                    short sh, sl2;
                    splitbf(fmaxf(acc[s][ks][e2], 0.f), sh, sl2);
                    hh[s][ks][e2] = sh; hl[s][ks][e2] = sl2;
                }

        f32x4 o[2][4];
#pragma unroll
        for (int mt2 = 0; mt2 < 4; ++mt2) {
            const f4 bb = LD4(b2c + mt2 * 16 + kg * 4);
#pragma unroll
            for (int s = 0; s < 2; ++s) o[s][mt2] = (f32x4){bb.x, bb.y, bb.z, bb.w};
        }
#pragma unroll
        for (int ks = 0; ks < 4; ++ks)
#pragma unroll
            for (int mt2 = 0; mt2 < 4; ++mt2) {
                const int fo4 = ((ks * 4 + mt2) * 64 + lane) * 4;
                const s4b wh = *(const s4b*)(w2lds + w2b + fo4);
                const s4b wl = *(const s4b*)(w2lds + w2b + 4096 + fo4);
#pragma unroll
                for (int s = 0; s < 2; ++s) {
                    o[s][mt2] = MFMA16(wh, hh[s][ks], o[s][mt2]);
                    o[s][mt2] = MFMA16(wl, hh[s][ks], o[s][mt2]);
                    o[s][mt2] = MFMA16(wh, hl[s][ks], o[s][mt2]);
                }
            }

        int iolA[2], vnA[2];
        uint4 pkh[2][2], pkl[2][2];
#pragma unroll
        for (int s = 0; s < 2; ++s) {
            const int p = pA[s];
            const int j = p & (Lh - 1);
            const int iol = 2 * p - j + (net ? Lh : 0);
            iolA[s] = iol;
            vnA[s]  = net ? v1A[s] : vxA[s];

            float z0 = 0.f, z1 = 0.f;
            union { short sv[16]; uint4 v[2]; } ph, pl;
#pragma unroll
            for (int mt2 = 0; mt2 < 4; ++mt2) {
#pragma unroll
                for (int e2 = 0; e2 < 4; ++e2) {
                    short sh, sl2;
                    splitbf(o[s][mt2][e2], sh, sl2);
                    ph.sv[mt2 * 4 + e2] = sh; pl.sv[mt2 * 4 + e2] = sl2;
                }
                const int f0 = mt2 * 16 + kg * 4;
                const f4 wA = LD4(cst + 320 + 2 * f0);
                const f4 wB = LD4(cst + 320 + 2 * f0 + 4);
                z0 += o[s][mt2][0] * wA.x + o[s][mt2][1] * wA.z +
                      o[s][mt2][2] * wB.x + o[s][mt2][3] * wB.z;
                z1 += o[s][mt2][0] * wA.y + o[s][mt2][1] * wA.w +
                      o[s][mt2][2] * wB.y + o[s][mt2][3] * wB.w;
            }
            pkh[s][0] = ph.v[0]; pkh[s][1] = ph.v[1];
            pkl[s][0] = pl.v[0]; pkl[s][1] = pl.v[1];
            z0 += __shfl_xor(z0, 16); z1 += __shfl_xor(z1, 16);
            z0 += __shfl_xor(z0, 32); z1 += __shfl_xor(z1, 32);

            if (kg == 0) {
                const int io = ch * 128 + iol;
                const float zz0 = z0 + llr_b[0], zz1 = z1 + llr_b[1];
                const float m   = fmaxf(zz0, zz1);
                const float ex0 = expf(zz0 - m), ex1 = expf(zz1 - m);
                const float inv = 1.0f / (ex0 + ex1);
                const float p0s = ex0 * inv, p1s = ex1 * inv;
                const float c0  = fminf(fmaxf(p0s, EPS_), 1.0f - EPS_);
                const float c1  = fminf(fmaxf(p1s, EPS_), 1.0f - EPS_);
                const int   lab = net ? (v1A[s] & 1) : vxA[s];
                const float loss = -logf(lab ? c1 : c0);
                loss_out[(b * T_ + t) * N_ + io] = loss;
                pscr[(size_t)(b * T_ + t) * N_ + io] = make_float2(p0s, p1s);
            }
        }
        __syncthreads();

#pragma unroll
        for (int s = 0; s < 2; ++s) {
            short* dh = &ehl[0][iolA[s] * ESTR + kg * 16];
            short* dl = &ehl[1][iolA[s] * ESTR + kg * 16];
            *(uint4*)dh       = pkh[s][0];
            *(uint4*)(dh + 8) = pkh[s][1];
            *(uint4*)dl       = pkl[s][0];
            *(uint4*)(dl + 8) = pkl[s][1];
            if (kg == 0) v_lds[iolA[s]] = vnA[s];
        }
        __syncthreads();
    }

    // ---- folded pred transpose: this block's 128 positions ----
    if (tid < 128) {
        const int io  = ch * 128 + tid;
        const int idx = b * N_ + io;
        float2 v[T_];
#pragma unroll
        for (int t = 0; t < T_; ++t)
            v[t] = pscr[(size_t)(b * T_ + t) * N_ + io];
        float* d1 = pred1 + (size_t)idx * (T_ * 2);
        float* d2 = pred2 + (size_t)idx * (T_ * 2);
#pragma unroll
        for (int q = 0; q < 6; ++q) {
            const f4 w = make_float4(v[2 * q].x, v[2 * q].y, v[2 * q + 1].x, v[2 * q + 1].y);
            *(f4*)(d1 + 4 * q) = w;
            *(f4*)(d2 + 4 * q) = w;
        }
    }
}

// ---------------------------------------------------------------------------
extern "C" void kernel_launch(void* const* d_in, const int* in_sizes, int n_in,
                              void* d_out, int out_size, void* d_ws, size_t ws_size,
                              hipStream_t stream)
{
    const int*   x      = (const int*)  d_in[0];
    const float* y      = (const float*)d_in[1];
    const float* emb_w1 = (const float*)d_in[2];
    const float* emb_b1 = (const float*)d_in[3];
    const float* emb_w2 = (const float*)d_in[4];
    const float* emb_b2 = (const float*)d_in[5];
    const float* cn_w1  = (const float*)d_in[6];
    const float* cn_b1  = (const float*)d_in[7];
    const float* cn_w2  = (const float*)d_in[8];
    const float* cn_b2  = (const float*)d_in[9];
    const float* bn_w1  = (const float*)d_in[10];
    const float* bn_b1  = (const float*)d_in[11];
    const float* bn_w2  = (const float*)d_in[12];
    const float* bn_b2  = (const float*)d_in[13];
    const float* llr_w  = (const float*)d_in[14];
    const float* llr_b  = (const float*)d_in[15];
    const float* label_emb = (const float*)d_in[16];

    float* out      = (float*)d_out;
    float* loss_out = out;
    float* pred1    = out + (size_t)B_ * T_ * N_;
    float* pred2    = pred1 + (size_t)B_ * N_ * T_ * 2;

    const size_t EPLANE = (size_t)B_ * N_ * D_;
    short* eh_a = (short*)d_ws;
    short* el_a = eh_a + EPLANE;
    int*   v_a  = (int*)(el_a + EPLANE);
    float2* pscr = (float2*)(v_a + B_ * N_);
    short* wblob = (short*)(pscr + (size_t)B_ * T_ * N_);
    float* contrib = (float*)(wblob + WBLOB_SHORTS);

    prep_kernel<<<dim3(65), dim3(256), 0, stream>>>(
        cn_w1, cn_w2, bn_w1, bn_w2, bn_b1, label_emb, emb_w2, wblob, contrib);

    fused_head<<<dim3(1024), dim3(256), 0, stream>>>(
        x, y, emb_w1, emb_b1, emb_b2,
        eh_a, el_a, v_a, wblob,
        cn_b1, cn_b2, bn_b2, contrib, llr_w, llr_b,
        loss_out, pscr);

    fused_tail<<<dim3(1024), dim3(256), 0, stream>>>(
        eh_a, el_a, v_a, wblob,
        cn_b1, cn_b2, bn_b2, contrib, llr_w, llr_b,
        loss_out, pscr, pred1, pred2);
}